// Round 1
// baseline (683.275 us; speedup 1.0000x reference)
//
#include <hip/hip_runtime.h>

// ============================================================================
// MoE block (top-2 of 8 experts), T=8192 tokens, d=1024, h=2048.
// R5: phase1/phase2 rebuilt as BK=64 double-buffered prefetch pipelines:
//   per K-tile: ds_read cur buf -> regs, issue next-tile global_load_lds,
//   MFMA, ONE __syncthreads() (latency overlaps compute; 4x fewer barriers).
// + XCD-chunked block remap (grid%8==0) so blocks sharing an expert's weight
//   panel run on the same XCD -> panel L2-resident.
// Rest (router/finalize/fill/gather/combine, atomic-free packed-Y combine)
// unchanged from R4.
//
// ws layout (bytes):
//   0       counts[8] / 64 offsets[9] / 128 cursors[8] / 192 tileoff[9]
//   256     topk_idx[16384] int
//   65792   topk_gate[16384] float
//   131328  block_probsum[2048*8] float
//   196864  assign_token[16384] int
//   262400  assign_gate[16384] float
//   327936  posinv[16384] int            (token -> packed row, x2)
//   1 MB    Xg[(16384+128) x 1024] bf16   (33.8 MB)
//   +       w1b[8*2048*1024] bf16         (33.6 MB)
//   +       w2b[8*1024*2048] bf16         (33.6 MB)
//   +       Hbuf[(16384+128) x 2048] bf16 (67.6 MB)
//   +       Y[(16384+128) x 1024] bf16    (33.8 MB)   total ~204 MB
// ============================================================================

#define TOKS 8192
#define DIMD 1024
#define HID  2048
#define NE   8

#define OFF_COUNTS   0
#define OFF_OFFSETS  64
#define OFF_CURSORS  128
#define OFF_TILEOFF  192
#define OFF_TOPKI    256
#define OFF_TOPKG    (OFF_TOPKI + TOKS*2*4)
#define OFF_BLKPS    (OFF_TOPKG + TOKS*2*4)
#define OFF_ATOK     (OFF_BLKPS + 2048*NE*4)
#define OFF_AGATE    (OFF_ATOK + TOKS*2*4)
#define OFF_PINV     (OFF_AGATE + TOKS*2*4)
#define OFF_XG       (1u << 20)
#define XG_ROWS      (TOKS*2 + 128)
#define OFF_W1B      (OFF_XG  + (size_t)XG_ROWS * DIMD * 2)
#define OFF_W2B      (OFF_W1B + (size_t)NE * HID * DIMD * 2)
#define OFF_H        (OFF_W2B + (size_t)NE * DIMD * HID * 2)
#define OFF_Y        (OFF_H   + (size_t)XG_ROWS * HID * 2)

typedef __bf16 bf16x8 __attribute__((ext_vector_type(8)));
typedef float  floatx4 __attribute__((ext_vector_type(4)));

__device__ __forceinline__ float bf2f(unsigned short u) {
    return __uint_as_float(((unsigned)u) << 16);
}
__device__ __forceinline__ unsigned short f2bf(float f) {
    unsigned u = __float_as_uint(f);
    unsigned r = (u + 0x7FFFu + ((u >> 16) & 1u)) >> 16;
    return (unsigned short)r;
}

#define GLOBAL_AS(p) ((const __attribute__((address_space(1))) unsigned int*)(p))
#define LDS_AS(p)    ((__attribute__((address_space(3))) unsigned int*)(p))

// ---------------------------------------------------------------------------
// Both weight tensors -> bf16 in one pass.
__global__ void convert_w_kernel(const float4* __restrict__ w1,
                                 ushort4* __restrict__ w1b, int n1,
                                 const float4* __restrict__ w2,
                                 ushort4* __restrict__ w2b, int n2) {
    int i = blockIdx.x * blockDim.x + threadIdx.x;
    int stride = gridDim.x * blockDim.x;
    int ntot = n1 + n2;
    for (; i < ntot; i += stride) {
        float4 v; ushort4 o;
        if (i < n1) v = w1[i]; else v = w2[i - n1];
        o.x = f2bf(v.x); o.y = f2bf(v.y); o.z = f2bf(v.z); o.w = f2bf(v.w);
        if (i < n1) w1b[i] = o; else w2b[i - n1] = o;
    }
}

// ---------------------------------------------------------------------------
// One wave per token: logits = x[t] . rw[e], softmax over 8, top-2, gates.
__global__ __launch_bounds__(256) void router_kernel(
    const float* __restrict__ x, const float* __restrict__ rw,
    int* __restrict__ topki, float* __restrict__ topkg,
    float* __restrict__ blkps)
{
    int wave = threadIdx.x >> 6;
    int lane = threadIdx.x & 63;
    int t = blockIdx.x * 4 + wave;
    const float* xt = x + (size_t)t * DIMD;

    float acc[NE];
#pragma unroll
    for (int e = 0; e < NE; e++) acc[e] = 0.f;
    for (int i = 0; i < DIMD / 64; i++) {
        float xv = xt[lane + 64 * i];
#pragma unroll
        for (int e = 0; e < NE; e++) acc[e] += xv * rw[e * DIMD + lane + 64 * i];
    }
#pragma unroll
    for (int off = 32; off > 0; off >>= 1) {
#pragma unroll
        for (int e = 0; e < NE; e++) acc[e] += __shfl_down(acc[e], off);
    }

    __shared__ float ps[4][NE];
    if (lane == 0) {
        float m = acc[0];
#pragma unroll
        for (int e = 1; e < NE; e++) m = fmaxf(m, acc[e]);
        float ex[NE], s = 0.f;
#pragma unroll
        for (int e = 0; e < NE; e++) { ex[e] = expf(acc[e] - m); s += ex[e]; }
        float inv = 1.f / s;
#pragma unroll
        for (int e = 0; e < NE; e++) ps[wave][e] = ex[e] * inv;

        int i0 = 0; float l0 = acc[0];
#pragma unroll
        for (int e = 1; e < NE; e++) if (acc[e] > l0) { l0 = acc[e]; i0 = e; }
        int i1 = -1; float l1 = -3.4e38f;
#pragma unroll
        for (int e = 0; e < NE; e++) if (e != i0 && acc[e] > l1) { l1 = acc[e]; i1 = e; }
        float e1 = expf(l1 - l0);
        float g0 = 1.f / (1.f + e1);
        float g1 = e1 * g0;
        topki[t * 2 + 0] = i0; topki[t * 2 + 1] = i1;
        topkg[t * 2 + 0] = g0; topkg[t * 2 + 1] = g1;
    }
    __syncthreads();
    if (threadIdx.x < NE) {
        float s = ps[0][threadIdx.x] + ps[1][threadIdx.x] + ps[2][threadIdx.x] + ps[3][threadIdx.x];
        blkps[blockIdx.x * NE + threadIdx.x] = s;
    }
}

// ---------------------------------------------------------------------------
// Single block: counts, offsets (packed row bases), cursors, 128-row tile
// prefix, aux loss. Vectorized int4/float4 reads.
__global__ __launch_bounds__(256) void finalize_kernel(
    const int* __restrict__ topki, const float* __restrict__ blkps,
    int* __restrict__ counts, int* __restrict__ offsets, int* __restrict__ cursors,
    int* __restrict__ tileoff, float* __restrict__ aux_out)
{
    __shared__ float psum[NE];
    __shared__ int cnt[NE];
    int tid = threadIdx.x;
    if (tid < NE) { psum[tid] = 0.f; cnt[tid] = 0; }
    __syncthreads();

    float lp[NE]; int lc[NE];
#pragma unroll
    for (int e = 0; e < NE; e++) { lp[e] = 0.f; lc[e] = 0; }
    const float4* bp4 = (const float4*)blkps;
    for (int i = tid; i < 2048 * NE / 4; i += 256) {
        float4 v = bp4[i];
        int eb = (4 * i) & 7;   // 0 or 4
        lp[eb + 0] += v.x; lp[eb + 1] += v.y; lp[eb + 2] += v.z; lp[eb + 3] += v.w;
    }
    const int4* ti4 = (const int4*)topki;
    for (int i = tid; i < TOKS * 2 / 4; i += 256) {
        int4 v = ti4[i];
        lc[v.x]++; lc[v.y]++; lc[v.z]++; lc[v.w]++;
    }
#pragma unroll
    for (int e = 0; e < NE; e++) { atomicAdd(&psum[e], lp[e]); atomicAdd(&cnt[e], lc[e]); }
    __syncthreads();

    if (tid == 0) {
        int off = 0, to = 0;
        for (int e = 0; e < NE; e++) {
            counts[e] = cnt[e];
            offsets[e] = off; cursors[e] = off;
            tileoff[e] = to;
            off += cnt[e];
            to += (cnt[e] + 127) >> 7;
        }
        offsets[NE] = off; tileoff[NE] = to;
        float aux = 0.f;
        for (int e = 0; e < NE; e++)
            aux += ((float)cnt[e] / (float)(TOKS * 2)) * (psum[e] / (float)TOKS);
        aux_out[0] = (float)NE * aux;
    }
}

// ---------------------------------------------------------------------------
// Build packed per-expert (token, gate) lists + inverse map token->position.
__global__ __launch_bounds__(64) void fill_kernel(
    const int* __restrict__ topki, const float* __restrict__ topkg,
    int* __restrict__ cursors, int* __restrict__ atok, float* __restrict__ agate,
    int* __restrict__ posinv)
{
    int lane = threadIdx.x;
    int t = blockIdx.x * 64 + lane;
    unsigned long long below = (lane == 63) ? 0x7FFFFFFFFFFFFFFFull
                                            : ((1ull << lane) - 1ull);
#pragma unroll
    for (int k = 0; k < 2; k++) {
        int e = topki[t * 2 + k];
        float g = topkg[t * 2 + k];
        for (int ee = 0; ee < NE; ee++) {
            bool pred = (e == ee);
            unsigned long long mask = __ballot(pred ? 1 : 0);
            if (mask) {
                int leader = __ffsll((unsigned long long)mask) - 1;
                int base = 0;
                if (lane == leader) base = atomicAdd(&cursors[ee], (int)__popcll(mask));
                base = __shfl(base, leader);
                if (pred) {
                    int pos = base + (int)__popcll(mask & below);
                    atok[pos] = t;
                    agate[pos] = g;
                    posinv[t * 2 + k] = pos;
                }
            }
        }
    }
}

// ---------------------------------------------------------------------------
// Gather x rows into packed assignment order, fp32 -> bf16.
__global__ __launch_bounds__(256) void gather_x_kernel(
    const float* __restrict__ x, const int* __restrict__ atok,
    ushort* __restrict__ Xg)
{
    int r = blockIdx.x;
    int tid = threadIdx.x;
    int tok = atok[r];
    float4 v = ((const float4*)(x + (size_t)tok * DIMD))[tid];
    ushort4 o;
    o.x = f2bf(v.x); o.y = f2bf(v.y); o.z = f2bf(v.z); o.w = f2bf(v.w);
    ((ushort4*)(Xg + (size_t)r * DIMD))[tid] = o;
}

// ---------------------------------------------------------------------------
// MFMA GEMM phase 1: H[r,:] = gelu(Xg[r,:] @ w1b[e]^T + b1[e]) (bf16 out).
// 128x128 tile, BK=64, 4 waves, double-buffered LDS prefetch pipeline:
//   ds_read cur -> regs, issue next-tile global_load_lds, MFMA, 1 barrier.
// XCD-chunked block remap keeps each expert's B panel L2-resident.
__global__ __launch_bounds__(256) void phase1_kernel(
    const ushort* __restrict__ Xg, const ushort* __restrict__ w1b,
    const float* __restrict__ b1,
    const int* __restrict__ counts, const int* __restrict__ offsets,
    const int* __restrict__ tileoff, unsigned short* __restrict__ Hbuf)
{
    const int NCOLT = HID / 128;   // 16
    int total = tileoff[NE] * NCOLT;
    // XCD-aware remap (gridDim.x % 8 == 0): physical bid -> logical idx so
    // each XCD owns a contiguous chunk of (rowt, ct) tiles.
    int q = (int)(gridDim.x >> 3);
    int idx = (int)(blockIdx.x & 7) * q + (int)(blockIdx.x >> 3);
    if (idx >= total) return;
    int ct = idx & (NCOLT - 1);
    int rowt = idx / NCOLT;
    int e = 0;
    while (rowt >= tileoff[e + 1]) e++;
    int row0 = (rowt - tileoff[e]) * 128;
    int cnt = counts[e];
    int base = offsets[e];
    int colbase = ct * 128;

    // [buf][A=0/B=1][khalf][128 rows x 32 cols as 16-row subtiles] = 64 KiB
    __shared__ ushort lds[2][2][2][128 * 32];

    int tid = threadIdx.x;
    int lane = tid & 63;
    int wave = tid >> 6;
    int wrow = wave >> 1, wcol = wave & 1;
    int l15 = lane & 15, quad = lane >> 4;

    const ushort* gA = Xg + (size_t)(base + row0 + 16 * (2 * wave) + l15) * DIMD + quad * 8;
    const ushort* gB = w1b + (size_t)e * HID * DIMD
                     + (size_t)(colbase + 16 * (2 * wave) + l15) * DIMD + quad * 8;

#define P1_STAGE(BUF, KOFF) do { \
    __builtin_amdgcn_global_load_lds(GLOBAL_AS(gA + (KOFF)),                  LDS_AS(&lds[BUF][0][0][(2*wave+0)*512]), 16, 0, 0); \
    __builtin_amdgcn_global_load_lds(GLOBAL_AS(gA + (KOFF) + 16*DIMD),        LDS_AS(&lds[BUF][0][0][(2*wave+1)*512]), 16, 0, 0); \
    __builtin_amdgcn_global_load_lds(GLOBAL_AS(gA + (KOFF) + 32),             LDS_AS(&lds[BUF][0][1][(2*wave+0)*512]), 16, 0, 0); \
    __builtin_amdgcn_global_load_lds(GLOBAL_AS(gA + (KOFF) + 32 + 16*DIMD),   LDS_AS(&lds[BUF][0][1][(2*wave+1)*512]), 16, 0, 0); \
    __builtin_amdgcn_global_load_lds(GLOBAL_AS(gB + (KOFF)),                  LDS_AS(&lds[BUF][1][0][(2*wave+0)*512]), 16, 0, 0); \
    __builtin_amdgcn_global_load_lds(GLOBAL_AS(gB + (KOFF) + 16*DIMD),        LDS_AS(&lds[BUF][1][0][(2*wave+1)*512]), 16, 0, 0); \
    __builtin_amdgcn_global_load_lds(GLOBAL_AS(gB + (KOFF) + 32),             LDS_AS(&lds[BUF][1][1][(2*wave+0)*512]), 16, 0, 0); \
    __builtin_amdgcn_global_load_lds(GLOBAL_AS(gB + (KOFF) + 32 + 16*DIMD),   LDS_AS(&lds[BUF][1][1][(2*wave+1)*512]), 16, 0, 0); \
} while (0)

    floatx4 acc[4][4];
#pragma unroll
    for (int i = 0; i < 4; i++)
#pragma unroll
        for (int j = 0; j < 4; j++) acc[i][j] = (floatx4){0.f, 0.f, 0.f, 0.f};

    P1_STAGE(0, 0);
    __syncthreads();          // drains vmcnt(0): buf0 ready

    int cur = 0;
    for (int kt = 0; kt < DIMD / 64 - 1; kt++) {
        // 1) register-load current fragments FIRST (no vmcnt dependency)
        bf16x8 a[2][4], b[2][4];
#pragma unroll
        for (int h = 0; h < 2; h++) {
            const bf16x8* fA = (const bf16x8*)&lds[cur][0][h][0];
            const bf16x8* fB = (const bf16x8*)&lds[cur][1][h][0];
#pragma unroll
            for (int i = 0; i < 4; i++) a[h][i] = fA[(4 * wrow + i) * 64 + lane];
#pragma unroll
            for (int j = 0; j < 4; j++) b[h][j] = fB[(4 * wcol + j) * 64 + lane];
        }
        // 2) issue next K-tile loads -> other buffer (overlaps MFMA below)
        P1_STAGE(cur ^ 1, (kt + 1) * 64);
        // 3) MFMA on current fragments
#pragma unroll
        for (int h = 0; h < 2; h++)
#pragma unroll
            for (int i = 0; i < 4; i++)
#pragma unroll
                for (int j = 0; j < 4; j++)
                    acc[i][j] = __builtin_amdgcn_mfma_f32_16x16x32_bf16(a[h][i], b[h][j], acc[i][j], 0, 0, 0);
        // 4) one barrier per K-tile: drains prefetch + guards buffer reuse
        __syncthreads();
        cur ^= 1;
    }
    {   // final K-tile: compute only
        bf16x8 a[2][4], b[2][4];
#pragma unroll
        for (int h = 0; h < 2; h++) {
            const bf16x8* fA = (const bf16x8*)&lds[cur][0][h][0];
            const bf16x8* fB = (const bf16x8*)&lds[cur][1][h][0];
#pragma unroll
            for (int i = 0; i < 4; i++) a[h][i] = fA[(4 * wrow + i) * 64 + lane];
#pragma unroll
            for (int j = 0; j < 4; j++) b[h][j] = fB[(4 * wcol + j) * 64 + lane];
        }
#pragma unroll
        for (int h = 0; h < 2; h++)
#pragma unroll
            for (int i = 0; i < 4; i++)
#pragma unroll
                for (int j = 0; j < 4; j++)
                    acc[i][j] = __builtin_amdgcn_mfma_f32_16x16x32_bf16(a[h][i], b[h][j], acc[i][j], 0, 0, 0);
    }
#undef P1_STAGE

    // epilogue: bias + exact GELU, bf16 store. C/D: col=lane&15, row=quad*4+reg
#pragma unroll
    for (int i = 0; i < 4; i++) {
#pragma unroll
        for (int r = 0; r < 4; r++) {
            int pr = row0 + 64 * wrow + 16 * i + quad * 4 + r;
            if (pr < cnt) {
                size_t hrow = (size_t)(base + pr) * HID;
#pragma unroll
                for (int j = 0; j < 4; j++) {
                    int col = colbase + 64 * wcol + 16 * j + l15;
                    float v = acc[i][j][r] + b1[e * HID + col];
                    v = 0.5f * v * (1.f + erff(v * 0.70710678118654752f));
                    Hbuf[hrow + col] = f2bf(v);
                }
            }
        }
    }
}

// ---------------------------------------------------------------------------
// MFMA GEMM phase 2: Y[r,:] = H[r,:] @ w2b[e]^T (no bias, no gate), bf16 out.
// Same BK=64 dbuf prefetch structure; strides HID, K = 2048.
__global__ __launch_bounds__(256) void phase2_kernel(
    const ushort* __restrict__ Hbuf, const ushort* __restrict__ w2b,
    const int* __restrict__ counts, const int* __restrict__ offsets,
    const int* __restrict__ tileoff, ushort* __restrict__ Y)
{
    const int NCOLT = DIMD / 128;  // 8
    int total = tileoff[NE] * NCOLT;
    int q = (int)(gridDim.x >> 3);
    int idx = (int)(blockIdx.x & 7) * q + (int)(blockIdx.x >> 3);
    if (idx >= total) return;
    int ct = idx & (NCOLT - 1);
    int rowt = idx / NCOLT;
    int e = 0;
    while (rowt >= tileoff[e + 1]) e++;
    int row0 = (rowt - tileoff[e]) * 128;
    int cnt = counts[e];
    int base = offsets[e];
    int colbase = ct * 128;

    __shared__ ushort lds[2][2][2][128 * 32];

    int tid = threadIdx.x;
    int lane = tid & 63;
    int wave = tid >> 6;
    int wrow = wave >> 1, wcol = wave & 1;
    int l15 = lane & 15, quad = lane >> 4;

    const ushort* gA = Hbuf + (size_t)(base + row0 + 16 * (2 * wave) + l15) * HID + quad * 8;
    const ushort* gB = w2b + (size_t)e * DIMD * HID
                     + (size_t)(colbase + 16 * (2 * wave) + l15) * HID + quad * 8;

#define P2_STAGE(BUF, KOFF) do { \
    __builtin_amdgcn_global_load_lds(GLOBAL_AS(gA + (KOFF)),                 LDS_AS(&lds[BUF][0][0][(2*wave+0)*512]), 16, 0, 0); \
    __builtin_amdgcn_global_load_lds(GLOBAL_AS(gA + (KOFF) + 16*HID),        LDS_AS(&lds[BUF][0][0][(2*wave+1)*512]), 16, 0, 0); \
    __builtin_amdgcn_global_load_lds(GLOBAL_AS(gA + (KOFF) + 32),            LDS_AS(&lds[BUF][0][1][(2*wave+0)*512]), 16, 0, 0); \
    __builtin_amdgcn_global_load_lds(GLOBAL_AS(gA + (KOFF) + 32 + 16*HID),   LDS_AS(&lds[BUF][0][1][(2*wave+1)*512]), 16, 0, 0); \
    __builtin_amdgcn_global_load_lds(GLOBAL_AS(gB + (KOFF)),                 LDS_AS(&lds[BUF][1][0][(2*wave+0)*512]), 16, 0, 0); \
    __builtin_amdgcn_global_load_lds(GLOBAL_AS(gB + (KOFF) + 16*HID),        LDS_AS(&lds[BUF][1][0][(2*wave+1)*512]), 16, 0, 0); \
    __builtin_amdgcn_global_load_lds(GLOBAL_AS(gB + (KOFF) + 32),            LDS_AS(&lds[BUF][1][1][(2*wave+0)*512]), 16, 0, 0); \
    __builtin_amdgcn_global_load_lds(GLOBAL_AS(gB + (KOFF) + 32 + 16*HID),   LDS_AS(&lds[BUF][1][1][(2*wave+1)*512]), 16, 0, 0); \
} while (0)

    floatx4 acc[4][4];
#pragma unroll
    for (int i = 0; i < 4; i++)
#pragma unroll
        for (int j = 0; j < 4; j++) acc[i][j] = (floatx4){0.f, 0.f, 0.f, 0.f};

    P2_STAGE(0, 0);
    __syncthreads();

    int cur = 0;
    for (int kt = 0; kt < HID / 64 - 1; kt++) {
        bf16x8 a[2][4], b[2][4];
#pragma unroll
        for (int h = 0; h < 2; h++) {
            const bf16x8* fA = (const bf16x8*)&lds[cur][0][h][0];
            const bf16x8* fB = (const bf16x8*)&lds[cur][1][h][0];
#pragma unroll
            for (int i = 0; i < 4; i++) a[h][i] = fA[(4 * wrow + i) * 64 + lane];
#pragma unroll
            for (int j = 0; j < 4; j++) b[h][j] = fB[(4 * wcol + j) * 64 + lane];
        }
        P2_STAGE(cur ^ 1, (kt + 1) * 64);
#pragma unroll
        for (int h = 0; h < 2; h++)
#pragma unroll
            for (int i = 0; i < 4; i++)
#pragma unroll
                for (int j = 0; j < 4; j++)
                    acc[i][j] = __builtin_amdgcn_mfma_f32_16x16x32_bf16(a[h][i], b[h][j], acc[i][j], 0, 0, 0);
        __syncthreads();
        cur ^= 1;
    }
    {
        bf16x8 a[2][4], b[2][4];
#pragma unroll
        for (int h = 0; h < 2; h++) {
            const bf16x8* fA = (const bf16x8*)&lds[cur][0][h][0];
            const bf16x8* fB = (const bf16x8*)&lds[cur][1][h][0];
#pragma unroll
            for (int i = 0; i < 4; i++) a[h][i] = fA[(4 * wrow + i) * 64 + lane];
#pragma unroll
            for (int j = 0; j < 4; j++) b[h][j] = fB[(4 * wcol + j) * 64 + lane];
        }
#pragma unroll
        for (int h = 0; h < 2; h++)
#pragma unroll
            for (int i = 0; i < 4; i++)
#pragma unroll
                for (int j = 0; j < 4; j++)
                    acc[i][j] = __builtin_amdgcn_mfma_f32_16x16x32_bf16(a[h][i], b[h][j], acc[i][j], 0, 0, 0);
    }
#undef P2_STAGE

    // epilogue: plain bf16 store of raw GEMM rows (bias+gate applied in combine)
#pragma unroll
    for (int i = 0; i < 4; i++) {
#pragma unroll
        for (int r = 0; r < 4; r++) {
            int pr = row0 + 64 * wrow + 16 * i + quad * 4 + r;
            if (pr < cnt) {
                size_t yrow = (size_t)(base + pr) * DIMD;
#pragma unroll
                for (int j = 0; j < 4; j++) {
                    int col = colbase + 64 * wcol + 16 * j + l15;
                    Y[yrow + col] = f2bf(acc[i][j][r]);
                }
            }
        }
    }
}

// ---------------------------------------------------------------------------
// Combine: out[t,:] = g0*Y[p0,:] + g1*Y[p1,:] + g0*b2[e0,:] + g1*b2[e1,:].
// One wave per token (4 tokens/block); lane covers 4 cols via ushort4.
__global__ __launch_bounds__(256) void combine_kernel(
    const ushort* __restrict__ Y, const float* __restrict__ b2,
    const int* __restrict__ topki, const float* __restrict__ topkg,
    const int* __restrict__ posinv, float* __restrict__ out)
{
    int wave = threadIdx.x >> 6;
    int lane = threadIdx.x & 63;
    int t = blockIdx.x * 4 + wave;
    int e0 = topki[t * 2 + 0], e1 = topki[t * 2 + 1];
    float g0 = topkg[t * 2 + 0], g1 = topkg[t * 2 + 1];
    int p0 = posinv[t * 2 + 0], p1 = posinv[t * 2 + 1];

    const ushort4* y0 = (const ushort4*)(Y + (size_t)p0 * DIMD);
    const ushort4* y1 = (const ushort4*)(Y + (size_t)p1 * DIMD);
    const float4* b20 = (const float4*)(b2 + (size_t)e0 * DIMD);
    const float4* b21 = (const float4*)(b2 + (size_t)e1 * DIMD);
    float4* o4 = (float4*)(out + (size_t)t * DIMD);

#pragma unroll
    for (int c = 0; c < DIMD / 4 / 64; c++) {   // 4 iterations
        int i = lane + 64 * c;
        ushort4 a = y0[i], b = y1[i];
        float4 ba = b20[i], bb = b21[i];
        float4 r;
        r.x = g0 * (bf2f(a.x) + ba.x) + g1 * (bf2f(b.x) + bb.x);
        r.y = g0 * (bf2f(a.y) + ba.y) + g1 * (bf2f(b.y) + bb.y);
        r.z = g0 * (bf2f(a.z) + ba.z) + g1 * (bf2f(b.z) + bb.z);
        r.w = g0 * (bf2f(a.w) + ba.w) + g1 * (bf2f(b.w) + bb.w);
        o4[i] = r;
    }
}

// ---------------------------------------------------------------------------
extern "C" void kernel_launch(void* const* d_in, const int* in_sizes, int n_in,
                              void* d_out, int out_size, void* d_ws, size_t ws_size,
                              hipStream_t stream) {
    const float* x  = (const float*)d_in[0];
    const float* rw = (const float*)d_in[1];
    const float* w1 = (const float*)d_in[2];
    const float* b1 = (const float*)d_in[3];
    const float* w2 = (const float*)d_in[4];
    const float* b2 = (const float*)d_in[5];
    float* out = (float*)d_out;

    char* ws = (char*)d_ws;
    int*   counts  = (int*)(ws + OFF_COUNTS);
    int*   offsets = (int*)(ws + OFF_OFFSETS);
    int*   cursors = (int*)(ws + OFF_CURSORS);
    int*   tileoff = (int*)(ws + OFF_TILEOFF);
    int*   topki   = (int*)(ws + OFF_TOPKI);
    float* topkg   = (float*)(ws + OFF_TOPKG);
    float* blkps   = (float*)(ws + OFF_BLKPS);
    int*   atok    = (int*)(ws + OFF_ATOK);
    float* agate   = (float*)(ws + OFF_AGATE);
    int*   posinv  = (int*)(ws + OFF_PINV);
    ushort* Xg     = (ushort*)(ws + OFF_XG);
    ushort* w1b    = (ushort*)(ws + OFF_W1B);
    ushort* w2b    = (ushort*)(ws + OFF_W2B);
    ushort* Hbuf   = (ushort*)(ws + OFF_H);
    ushort* Y      = (ushort*)(ws + OFF_Y);

    // weight conversions (independent of routing), one pass
    convert_w_kernel<<<8192, 256, 0, stream>>>(
        (const float4*)w1, (ushort4*)w1b, NE * HID * DIMD / 4,
        (const float4*)w2, (ushort4*)w2b, NE * DIMD * HID / 4);

    router_kernel<<<TOKS / 4, 256, 0, stream>>>(x, rw, topki, topkg, blkps);
    finalize_kernel<<<1, 256, 0, stream>>>(topki, blkps, counts, offsets, cursors,
                                           tileoff, out + (size_t)TOKS * DIMD);
    fill_kernel<<<TOKS / 64, 64, 0, stream>>>(topki, topkg, cursors, atok, agate,
                                              posinv);
    gather_x_kernel<<<TOKS * 2, 256, 0, stream>>>(x, atok, Xg);

    // worst-case 128-row tiles: sum_e ceil(cnt_e/128) <= 16384/128 + 7 = 135
    // grids are multiples of 8 (XCD remap requirement): 135*16=2160, 135*8=1080
    phase1_kernel<<<135 * (HID / 128), 256, 0, stream>>>(
        Xg, w1b, b1, counts, offsets, tileoff, Hbuf);
    phase2_kernel<<<135 * (DIMD / 128), 256, 0, stream>>>(
        Hbuf, w2b, counts, offsets, tileoff, Y);
    combine_kernel<<<TOKS / 4, 256, 0, stream>>>(Y, b2, topki, topkg, posinv, out);
}

// Round 2
// 629.333 us; speedup vs baseline: 1.0857x; 1.0857x over previous
//
#include <hip/hip_runtime.h>

// ============================================================================
// MoE block (top-2 of 8 experts), T=8192 tokens, d=1024, h=2048.
// R6: phase1/phase2 rebuilt on the 256x256 2-phase template (T3 minimum
// recipe, m230: 682 TF): BM=BN=256, BK=64, 8 waves (512 thr), 128 KiB dbuf
// LDS, per K-tile: {issue 8x global_load_lds -> other buf; ds_read frags;
// 64 MFMA; one __syncthreads}. Compute-per-barrier (~620 cy/SIMD) now
// exceeds load latency, so prefetch completes under MFMA even at 1 blk/CU.
// Linear chunked LDS (16-row x 32-col 1KB chunks, same fragment permutation
// as verified R4), no swizzle / no setprio (both null at 2-phase).
// Bijective XCD-chunk remap (m204) on both GEMM grids.
//
// ws layout (bytes):
//   0       counts[8] / 64 offsets[9] / 128 cursors[8] / 192 tileoff[9]
//   256     topk_idx[16384] int
//   65792   topk_gate[16384] float
//   131328  block_probsum[2048*8] float
//   196864  assign_token[16384] int
//   262400  assign_gate[16384] float
//   327936  posinv[16384] int            (token -> packed row, x2)
//   1 MB    Xg[(16384+256) x 1024] bf16
//   +       w1b[8*2048*1024] bf16
//   +       w2b[8*1024*2048] bf16
//   +       Hbuf[(16384+256) x 2048] bf16
//   +       Y[(16384+256) x 1024] bf16    total ~205 MB
// ============================================================================

#define TOKS 8192
#define DIMD 1024
#define HID  2048
#define NE   8

#define OFF_COUNTS   0
#define OFF_OFFSETS  64
#define OFF_CURSORS  128
#define OFF_TILEOFF  192
#define OFF_TOPKI    256
#define OFF_TOPKG    (OFF_TOPKI + TOKS*2*4)
#define OFF_BLKPS    (OFF_TOPKG + TOKS*2*4)
#define OFF_ATOK     (OFF_BLKPS + 2048*NE*4)
#define OFF_AGATE    (OFF_ATOK + TOKS*2*4)
#define OFF_PINV     (OFF_AGATE + TOKS*2*4)
#define OFF_XG       (1u << 20)
#define XG_ROWS      (TOKS*2 + 256)
#define OFF_W1B      (OFF_XG  + (size_t)XG_ROWS * DIMD * 2)
#define OFF_W2B      (OFF_W1B + (size_t)NE * HID * DIMD * 2)
#define OFF_H        (OFF_W2B + (size_t)NE * DIMD * HID * 2)
#define OFF_Y        (OFF_H   + (size_t)XG_ROWS * HID * 2)

typedef __bf16 bf16x8 __attribute__((ext_vector_type(8)));
typedef float  floatx4 __attribute__((ext_vector_type(4)));

__device__ __forceinline__ float bf2f(unsigned short u) {
    return __uint_as_float(((unsigned)u) << 16);
}
__device__ __forceinline__ unsigned short f2bf(float f) {
    unsigned u = __float_as_uint(f);
    unsigned r = (u + 0x7FFFu + ((u >> 16) & 1u)) >> 16;
    return (unsigned short)r;
}

#define GLOBAL_AS(p) ((const __attribute__((address_space(1))) unsigned int*)(p))
#define LDS_AS(p)    ((__attribute__((address_space(3))) unsigned int*)(p))

// m204 bijective XCD-chunk remap: physical bid -> logical idx.
__device__ __forceinline__ int xcd_remap(int bid, int nwg) {
    int xcd = bid & 7, pos = bid >> 3;
    int q = nwg >> 3, r = nwg & 7;
    int start = (xcd < r) ? xcd * (q + 1) : r * (q + 1) + (xcd - r) * q;
    return start + pos;
}

// ---------------------------------------------------------------------------
// Both weight tensors -> bf16 in one pass.
__global__ void convert_w_kernel(const float4* __restrict__ w1,
                                 ushort4* __restrict__ w1b, int n1,
                                 const float4* __restrict__ w2,
                                 ushort4* __restrict__ w2b, int n2) {
    int i = blockIdx.x * blockDim.x + threadIdx.x;
    int stride = gridDim.x * blockDim.x;
    int ntot = n1 + n2;
    for (; i < ntot; i += stride) {
        float4 v; ushort4 o;
        if (i < n1) v = w1[i]; else v = w2[i - n1];
        o.x = f2bf(v.x); o.y = f2bf(v.y); o.z = f2bf(v.z); o.w = f2bf(v.w);
        if (i < n1) w1b[i] = o; else w2b[i - n1] = o;
    }
}

// ---------------------------------------------------------------------------
// One wave per token: logits = x[t] . rw[e], softmax over 8, top-2, gates.
__global__ __launch_bounds__(256) void router_kernel(
    const float* __restrict__ x, const float* __restrict__ rw,
    int* __restrict__ topki, float* __restrict__ topkg,
    float* __restrict__ blkps)
{
    int wave = threadIdx.x >> 6;
    int lane = threadIdx.x & 63;
    int t = blockIdx.x * 4 + wave;
    const float* xt = x + (size_t)t * DIMD;

    float acc[NE];
#pragma unroll
    for (int e = 0; e < NE; e++) acc[e] = 0.f;
    for (int i = 0; i < DIMD / 64; i++) {
        float xv = xt[lane + 64 * i];
#pragma unroll
        for (int e = 0; e < NE; e++) acc[e] += xv * rw[e * DIMD + lane + 64 * i];
    }
#pragma unroll
    for (int off = 32; off > 0; off >>= 1) {
#pragma unroll
        for (int e = 0; e < NE; e++) acc[e] += __shfl_down(acc[e], off);
    }

    __shared__ float ps[4][NE];
    if (lane == 0) {
        float m = acc[0];
#pragma unroll
        for (int e = 1; e < NE; e++) m = fmaxf(m, acc[e]);
        float ex[NE], s = 0.f;
#pragma unroll
        for (int e = 0; e < NE; e++) { ex[e] = expf(acc[e] - m); s += ex[e]; }
        float inv = 1.f / s;
#pragma unroll
        for (int e = 0; e < NE; e++) ps[wave][e] = ex[e] * inv;

        int i0 = 0; float l0 = acc[0];
#pragma unroll
        for (int e = 1; e < NE; e++) if (acc[e] > l0) { l0 = acc[e]; i0 = e; }
        int i1 = -1; float l1 = -3.4e38f;
#pragma unroll
        for (int e = 0; e < NE; e++) if (e != i0 && acc[e] > l1) { l1 = acc[e]; i1 = e; }
        float e1 = expf(l1 - l0);
        float g0 = 1.f / (1.f + e1);
        float g1 = e1 * g0;
        topki[t * 2 + 0] = i0; topki[t * 2 + 1] = i1;
        topkg[t * 2 + 0] = g0; topkg[t * 2 + 1] = g1;
    }
    __syncthreads();
    if (threadIdx.x < NE) {
        float s = ps[0][threadIdx.x] + ps[1][threadIdx.x] + ps[2][threadIdx.x] + ps[3][threadIdx.x];
        blkps[blockIdx.x * NE + threadIdx.x] = s;
    }
}

// ---------------------------------------------------------------------------
// Single block: counts, offsets (packed row bases), cursors, 256-row tile
// prefix, aux loss. Vectorized int4/float4 reads.
__global__ __launch_bounds__(256) void finalize_kernel(
    const int* __restrict__ topki, const float* __restrict__ blkps,
    int* __restrict__ counts, int* __restrict__ offsets, int* __restrict__ cursors,
    int* __restrict__ tileoff, float* __restrict__ aux_out)
{
    __shared__ float psum[NE];
    __shared__ int cnt[NE];
    int tid = threadIdx.x;
    if (tid < NE) { psum[tid] = 0.f; cnt[tid] = 0; }
    __syncthreads();

    float lp[NE]; int lc[NE];
#pragma unroll
    for (int e = 0; e < NE; e++) { lp[e] = 0.f; lc[e] = 0; }
    const float4* bp4 = (const float4*)blkps;
    for (int i = tid; i < 2048 * NE / 4; i += 256) {
        float4 v = bp4[i];
        int eb = (4 * i) & 7;   // 0 or 4
        lp[eb + 0] += v.x; lp[eb + 1] += v.y; lp[eb + 2] += v.z; lp[eb + 3] += v.w;
    }
    const int4* ti4 = (const int4*)topki;
    for (int i = tid; i < TOKS * 2 / 4; i += 256) {
        int4 v = ti4[i];
        lc[v.x]++; lc[v.y]++; lc[v.z]++; lc[v.w]++;
    }
#pragma unroll
    for (int e = 0; e < NE; e++) { atomicAdd(&psum[e], lp[e]); atomicAdd(&cnt[e], lc[e]); }
    __syncthreads();

    if (tid == 0) {
        int off = 0, to = 0;
        for (int e = 0; e < NE; e++) {
            counts[e] = cnt[e];
            offsets[e] = off; cursors[e] = off;
            tileoff[e] = to;
            off += cnt[e];
            to += (cnt[e] + 255) >> 8;     // 256-row tiles now
        }
        offsets[NE] = off; tileoff[NE] = to;
        float aux = 0.f;
        for (int e = 0; e < NE; e++)
            aux += ((float)cnt[e] / (float)(TOKS * 2)) * (psum[e] / (float)TOKS);
        aux_out[0] = (float)NE * aux;
    }
}

// ---------------------------------------------------------------------------
// Build packed per-expert (token, gate) lists + inverse map token->position.
__global__ __launch_bounds__(64) void fill_kernel(
    const int* __restrict__ topki, const float* __restrict__ topkg,
    int* __restrict__ cursors, int* __restrict__ atok, float* __restrict__ agate,
    int* __restrict__ posinv)
{
    int lane = threadIdx.x;
    int t = blockIdx.x * 64 + lane;
    unsigned long long below = (lane == 63) ? 0x7FFFFFFFFFFFFFFFull
                                            : ((1ull << lane) - 1ull);
#pragma unroll
    for (int k = 0; k < 2; k++) {
        int e = topki[t * 2 + k];
        float g = topkg[t * 2 + k];
        for (int ee = 0; ee < NE; ee++) {
            bool pred = (e == ee);
            unsigned long long mask = __ballot(pred ? 1 : 0);
            if (mask) {
                int leader = __ffsll((unsigned long long)mask) - 1;
                int base = 0;
                if (lane == leader) base = atomicAdd(&cursors[ee], (int)__popcll(mask));
                base = __shfl(base, leader);
                if (pred) {
                    int pos = base + (int)__popcll(mask & below);
                    atok[pos] = t;
                    agate[pos] = g;
                    posinv[t * 2 + k] = pos;
                }
            }
        }
    }
}

// ---------------------------------------------------------------------------
// Gather x rows into packed assignment order, fp32 -> bf16.
__global__ __launch_bounds__(256) void gather_x_kernel(
    const float* __restrict__ x, const int* __restrict__ atok,
    ushort* __restrict__ Xg)
{
    int r = blockIdx.x;
    int tid = threadIdx.x;
    int tok = atok[r];
    float4 v = ((const float4*)(x + (size_t)tok * DIMD))[tid];
    ushort4 o;
    o.x = f2bf(v.x); o.y = f2bf(v.y); o.z = f2bf(v.z); o.w = f2bf(v.w);
    ((ushort4*)(Xg + (size_t)r * DIMD))[tid] = o;
}

// ===========================================================================
// 256x256 2-phase GEMM core, shared by phase1/phase2.
// LDS: [2 bufs][64 chunks][512 ushort] = 128 KiB. Chunk = 16 rows x 32 k-cols
// (1 KB), internal layout: lane l holds row (l&15), k-cols (l>>4)*8.. (the
// MFMA A/B fragment permutation, verified in R4). Chunks 0..31 = A-tile
// (subtile s, khalf h -> chunk s*2+h), 32..63 = B-tile.
// Each wave stages its 8 chunks (wave*8+i) per K-tile: exact 1:1 coverage.
// ===========================================================================

// ---------------------------------------------------------------------------
// Phase 1: H = gelu(Xg @ w1b[e]^T + b1[e]),  M=sum cnt, N=2048, K=1024.
__global__ __launch_bounds__(512, 2) void phase1_kernel(
    const ushort* __restrict__ Xg, const ushort* __restrict__ w1b,
    const float* __restrict__ b1,
    const int* __restrict__ counts, const int* __restrict__ offsets,
    const int* __restrict__ tileoff, unsigned short* __restrict__ Hbuf)
{
    const int LD = DIMD;           // K-stride of both A (Xg) and B (w1b)
    const int NT = DIMD / 64;      // 16 K-tiles
    const int NCOLT = HID / 256;   // 8 col tiles
    int total = tileoff[NE] * NCOLT;
    int idx = xcd_remap((int)blockIdx.x, (int)gridDim.x);
    if (idx >= total) return;
    int ct = idx & (NCOLT - 1);
    int rowt = idx / NCOLT;
    int e = 0;
    while (rowt >= tileoff[e + 1]) e++;
    int row0 = (rowt - tileoff[e]) * 256;
    int cnt = counts[e];
    int base = offsets[e];
    int colbase = ct * 256;

    __shared__ ushort lds[2][64][512];   // 128 KiB

    int tid = threadIdx.x;
    int lane = tid & 63;
    int wave = tid >> 6;          // 0..7
    int wr = wave >> 2, wc = wave & 3;   // wave tile: 128 rows x 64 cols
    int l15 = lane & 15, quad = lane >> 4;

    const ushort* gApanel = Xg + (size_t)(base + row0) * LD;
    const ushort* gBpanel = w1b + (size_t)e * HID * DIMD + (size_t)colbase * LD;

    // per-thread staging sources: chunk = wave*8+i; lane covers row (lane&15),
    // k-col (lane>>4)*8 of the chunk's 16x32 subtile.
    const ushort* src[8];
#pragma unroll
    for (int i = 0; i < 8; i++) {
        int chunk = wave * 8 + i;
        int tensor = chunk >> 5;
        int r = chunk & 31;
        int s = r >> 1, h = r & 1;
        const ushort* bse = tensor ? gBpanel : gApanel;
        src[i] = bse + (size_t)(s * 16 + l15) * LD + h * 32 + quad * 8;
    }

#define STAGE(BUF) do { \
    _Pragma("unroll") \
    for (int i = 0; i < 8; i++) { \
        __builtin_amdgcn_global_load_lds(GLOBAL_AS(src[i]), LDS_AS(&lds[BUF][wave*8 + i][0]), 16, 0, 0); \
        src[i] += 64; \
    } \
} while (0)

    floatx4 acc[8][4];
#pragma unroll
    for (int i = 0; i < 8; i++)
#pragma unroll
        for (int j = 0; j < 4; j++) acc[i][j] = (floatx4){0.f, 0.f, 0.f, 0.f};

    auto compute = [&](int bufidx) {
        const bf16x8* C = (const bf16x8*)&lds[bufidx][0][0];
#pragma unroll
        for (int h = 0; h < 2; h++) {
            bf16x8 a[8], b[4];
#pragma unroll
            for (int i = 0; i < 8; i++) a[i] = C[((wr * 8 + i) * 2 + h) * 64 + lane];
#pragma unroll
            for (int j = 0; j < 4; j++) b[j] = C[(32 + (wc * 4 + j) * 2 + h) * 64 + lane];
#pragma unroll
            for (int i = 0; i < 8; i++)
#pragma unroll
                for (int j = 0; j < 4; j++)
                    acc[i][j] = __builtin_amdgcn_mfma_f32_16x16x32_bf16(a[i], b[j], acc[i][j], 0, 0, 0);
        }
    };

    STAGE(0);
    __syncthreads();              // buf0 ready (vmcnt drained)
    int cur = 0;
    for (int kt = 0; kt < NT - 1; kt++) {
        STAGE(cur ^ 1);           // issue next K-tile first (flies under MFMA)
        compute(cur);
        __syncthreads();          // drains prefetch + frag reads
        cur ^= 1;
    }
    compute(cur);
#undef STAGE

    // epilogue: bias + exact GELU, bf16 store. C/D: col=lane&15, row=quad*4+reg
    float b1v[4];
#pragma unroll
    for (int j = 0; j < 4; j++)
        b1v[j] = b1[e * HID + colbase + 64 * wc + 16 * j + l15];
#pragma unroll
    for (int i = 0; i < 8; i++) {
#pragma unroll
        for (int rr = 0; rr < 4; rr++) {
            int pr = row0 + 128 * wr + 16 * i + quad * 4 + rr;
            if (pr < cnt) {
                size_t hrow = (size_t)(base + pr) * HID;
#pragma unroll
                for (int j = 0; j < 4; j++) {
                    int col = colbase + 64 * wc + 16 * j + l15;
                    float v = acc[i][j][rr] + b1v[j];
                    v = 0.5f * v * (1.f + erff(v * 0.70710678118654752f));
                    Hbuf[hrow + col] = f2bf(v);
                }
            }
        }
    }
}

// ---------------------------------------------------------------------------
// Phase 2: Y = H @ w2b[e]^T,  M=sum cnt, N=1024, K=2048.
__global__ __launch_bounds__(512, 2) void phase2_kernel(
    const ushort* __restrict__ Hbuf, const ushort* __restrict__ w2b,
    const int* __restrict__ counts, const int* __restrict__ offsets,
    const int* __restrict__ tileoff, ushort* __restrict__ Y)
{
    const int LD = HID;            // K-stride of both A (Hbuf) and B (w2b)
    const int NT = HID / 64;       // 32 K-tiles
    const int NCOLT = DIMD / 256;  // 4 col tiles
    int total = tileoff[NE] * NCOLT;
    int idx = xcd_remap((int)blockIdx.x, (int)gridDim.x);
    if (idx >= total) return;
    int ct = idx & (NCOLT - 1);
    int rowt = idx / NCOLT;
    int e = 0;
    while (rowt >= tileoff[e + 1]) e++;
    int row0 = (rowt - tileoff[e]) * 256;
    int cnt = counts[e];
    int base = offsets[e];
    int colbase = ct * 256;

    __shared__ ushort lds[2][64][512];   // 128 KiB

    int tid = threadIdx.x;
    int lane = tid & 63;
    int wave = tid >> 6;
    int wr = wave >> 2, wc = wave & 3;
    int l15 = lane & 15, quad = lane >> 4;

    const ushort* gApanel = Hbuf + (size_t)(base + row0) * LD;
    const ushort* gBpanel = w2b + (size_t)e * DIMD * HID + (size_t)colbase * LD;

    const ushort* src[8];
#pragma unroll
    for (int i = 0; i < 8; i++) {
        int chunk = wave * 8 + i;
        int tensor = chunk >> 5;
        int r = chunk & 31;
        int s = r >> 1, h = r & 1;
        const ushort* bse = tensor ? gBpanel : gApanel;
        src[i] = bse + (size_t)(s * 16 + l15) * LD + h * 32 + quad * 8;
    }

#define STAGE(BUF) do { \
    _Pragma("unroll") \
    for (int i = 0; i < 8; i++) { \
        __builtin_amdgcn_global_load_lds(GLOBAL_AS(src[i]), LDS_AS(&lds[BUF][wave*8 + i][0]), 16, 0, 0); \
        src[i] += 64; \
    } \
} while (0)

    floatx4 acc[8][4];
#pragma unroll
    for (int i = 0; i < 8; i++)
#pragma unroll
        for (int j = 0; j < 4; j++) acc[i][j] = (floatx4){0.f, 0.f, 0.f, 0.f};

    auto compute = [&](int bufidx) {
        const bf16x8* C = (const bf16x8*)&lds[bufidx][0][0];
#pragma unroll
        for (int h = 0; h < 2; h++) {
            bf16x8 a[8], b[4];
#pragma unroll
            for (int i = 0; i < 8; i++) a[i] = C[((wr * 8 + i) * 2 + h) * 64 + lane];
#pragma unroll
            for (int j = 0; j < 4; j++) b[j] = C[(32 + (wc * 4 + j) * 2 + h) * 64 + lane];
#pragma unroll
            for (int i = 0; i < 8; i++)
#pragma unroll
                for (int j = 0; j < 4; j++)
                    acc[i][j] = __builtin_amdgcn_mfma_f32_16x16x32_bf16(a[i], b[j], acc[i][j], 0, 0, 0);
        }
    };

    STAGE(0);
    __syncthreads();
    int cur = 0;
    for (int kt = 0; kt < NT - 1; kt++) {
        STAGE(cur ^ 1);
        compute(cur);
        __syncthreads();
        cur ^= 1;
    }
    compute(cur);
#undef STAGE

    // epilogue: plain bf16 store (bias+gate applied in combine)
#pragma unroll
    for (int i = 0; i < 8; i++) {
#pragma unroll
        for (int rr = 0; rr < 4; rr++) {
            int pr = row0 + 128 * wr + 16 * i + quad * 4 + rr;
            if (pr < cnt) {
                size_t yrow = (size_t)(base + pr) * DIMD;
#pragma unroll
                for (int j = 0; j < 4; j++) {
                    int col = colbase + 64 * wc + 16 * j + l15;
                    Y[yrow + col] = f2bf(acc[i][j][rr]);
                }
            }
        }
    }
}

// ---------------------------------------------------------------------------
// Combine: out[t,:] = g0*(Y[p0,:]+b2[e0,:]) + g1*(Y[p1,:]+b2[e1,:]).
__global__ __launch_bounds__(256) void combine_kernel(
    const ushort* __restrict__ Y, const float* __restrict__ b2,
    const int* __restrict__ topki, const float* __restrict__ topkg,
    const int* __restrict__ posinv, float* __restrict__ out)
{
    int wave = threadIdx.x >> 6;
    int lane = threadIdx.x & 63;
    int t = blockIdx.x * 4 + wave;
    int e0 = topki[t * 2 + 0], e1 = topki[t * 2 + 1];
    float g0 = topkg[t * 2 + 0], g1 = topkg[t * 2 + 1];
    int p0 = posinv[t * 2 + 0], p1 = posinv[t * 2 + 1];

    const ushort4* y0 = (const ushort4*)(Y + (size_t)p0 * DIMD);
    const ushort4* y1 = (const ushort4*)(Y + (size_t)p1 * DIMD);
    const float4* b20 = (const float4*)(b2 + (size_t)e0 * DIMD);
    const float4* b21 = (const float4*)(b2 + (size_t)e1 * DIMD);
    float4* o4 = (float4*)(out + (size_t)t * DIMD);

#pragma unroll
    for (int c = 0; c < DIMD / 4 / 64; c++) {   // 4 iterations
        int i = lane + 64 * c;
        ushort4 a = y0[i], b = y1[i];
        float4 ba = b20[i], bb = b21[i];
        float4 r;
        r.x = g0 * (bf2f(a.x) + ba.x) + g1 * (bf2f(b.x) + bb.x);
        r.y = g0 * (bf2f(a.y) + ba.y) + g1 * (bf2f(b.y) + bb.y);
        r.z = g0 * (bf2f(a.z) + ba.z) + g1 * (bf2f(b.z) + bb.z);
        r.w = g0 * (bf2f(a.w) + ba.w) + g1 * (bf2f(b.w) + bb.w);
        o4[i] = r;
    }
}

// ---------------------------------------------------------------------------
extern "C" void kernel_launch(void* const* d_in, const int* in_sizes, int n_in,
                              void* d_out, int out_size, void* d_ws, size_t ws_size,
                              hipStream_t stream) {
    const float* x  = (const float*)d_in[0];
    const float* rw = (const float*)d_in[1];
    const float* w1 = (const float*)d_in[2];
    const float* b1 = (const float*)d_in[3];
    const float* w2 = (const float*)d_in[4];
    const float* b2 = (const float*)d_in[5];
    float* out = (float*)d_out;

    char* ws = (char*)d_ws;
    int*   counts  = (int*)(ws + OFF_COUNTS);
    int*   offsets = (int*)(ws + OFF_OFFSETS);
    int*   cursors = (int*)(ws + OFF_CURSORS);
    int*   tileoff = (int*)(ws + OFF_TILEOFF);
    int*   topki   = (int*)(ws + OFF_TOPKI);
    float* topkg   = (float*)(ws + OFF_TOPKG);
    float* blkps   = (float*)(ws + OFF_BLKPS);
    int*   atok    = (int*)(ws + OFF_ATOK);
    float* agate   = (float*)(ws + OFF_AGATE);
    int*   posinv  = (int*)(ws + OFF_PINV);
    ushort* Xg     = (ushort*)(ws + OFF_XG);
    ushort* w1b    = (ushort*)(ws + OFF_W1B);
    ushort* w2b    = (ushort*)(ws + OFF_W2B);
    ushort* Hbuf   = (ushort*)(ws + OFF_H);
    ushort* Y      = (ushort*)(ws + OFF_Y);

    // weight conversions (independent of routing), one pass
    convert_w_kernel<<<8192, 256, 0, stream>>>(
        (const float4*)w1, (ushort4*)w1b, NE * HID * DIMD / 4,
        (const float4*)w2, (ushort4*)w2b, NE * DIMD * HID / 4);

    router_kernel<<<TOKS / 4, 256, 0, stream>>>(x, rw, topki, topkg, blkps);
    finalize_kernel<<<1, 256, 0, stream>>>(topki, blkps, counts, offsets, cursors,
                                           tileoff, out + (size_t)TOKS * DIMD);
    fill_kernel<<<TOKS / 64, 64, 0, stream>>>(topki, topkg, cursors, atok, agate,
                                              posinv);
    gather_x_kernel<<<TOKS * 2, 256, 0, stream>>>(x, atok, Xg);

    // worst-case 256-row tiles: sum_e ceil(cnt_e/256) <= 16384/256 + 7 = 71
    phase1_kernel<<<71 * (HID / 256), 512, 0, stream>>>(
        Xg, w1b, b1, counts, offsets, tileoff, Hbuf);
    phase2_kernel<<<71 * (DIMD / 256), 512, 0, stream>>>(
        Hbuf, w2b, counts, offsets, tileoff, Y);
    combine_kernel<<<TOKS / 4, 256, 0, stream>>>(Y, b2, topki, topkg, posinv, out);
}

// Round 3
// 591.312 us; speedup vs baseline: 1.1555x; 1.0643x over previous
//
#include <hip/hip_runtime.h>

// ============================================================================
// MoE block (top-2 of 8 experts), T=8192 tokens, d=1024, h=2048.
// R7: phase1/phase2 on the 256x256 8-phase counted-vmcnt template (T3+T4+T5,
// m201-style) in plain HIP. Per K-tile (BK=64): 4 C-quadrant phases, each
// {ds_read frags, stage 1 half-tile (2 global_load_lds/wave), raw s_barrier,
// lgkmcnt(0)+sched_barrier(0), setprio(1), 16 MFMA, setprio(0), s_barrier}.
// Loads stay in flight ACROSS barriers; one s_waitcnt vmcnt(4) per K-tile
// group (never 0 in steady state). Stage ledger (proven):
//   group u: p1 stages Ah1(u+1)->buf[(u+1)&1]  (slot dead since p3(u-1))
//            p2 stages Bh0(u+1)->buf[(u+1)&1]  (slot dead since p4(u-1))
//            p3 stages Ah0(u+2)->buf[u&1]      (slot dead after p1(u))
//            p4 stages Bh1(u+2)->buf[u&1]      (slot dead after p2(u))
//   invariant at each group-u end (vmcnt(4)): all of tile u+1 complete,
//   {Ah0(u+2), Bh1(u+2)} in flight. Tail groups force vmcnt(0).
// Quadrant order (Mlo,Nlo)(Mlo,Nhi)(Mhi,Nhi)(Mhi,Nlo) with a-frag reuse
// p1->p2, p3->p4 and b-frag reuse p2->p3 (28 ds_read_b128 / K-tile / wave).
// LDS chunk layout identical to verified R6 (conflict-free, 0 measured).
// ============================================================================

#define TOKS 8192
#define DIMD 1024
#define HID  2048
#define NE   8

#define OFF_COUNTS   0
#define OFF_OFFSETS  64
#define OFF_CURSORS  128
#define OFF_TILEOFF  192
#define OFF_TOPKI    256
#define OFF_TOPKG    (OFF_TOPKI + TOKS*2*4)
#define OFF_BLKPS    (OFF_TOPKG + TOKS*2*4)
#define OFF_ATOK     (OFF_BLKPS + 2048*NE*4)
#define OFF_AGATE    (OFF_ATOK + TOKS*2*4)
#define OFF_PINV     (OFF_AGATE + TOKS*2*4)
#define OFF_XG       (1u << 20)
#define XG_ROWS      (TOKS*2 + 256)
#define OFF_W1B      (OFF_XG  + (size_t)XG_ROWS * DIMD * 2)
#define OFF_W2B      (OFF_W1B + (size_t)NE * HID * DIMD * 2)
#define OFF_H        (OFF_W2B + (size_t)NE * DIMD * HID * 2)
#define OFF_Y        (OFF_H   + (size_t)XG_ROWS * HID * 2)

typedef __bf16 bf16x8 __attribute__((ext_vector_type(8)));
typedef float  floatx4 __attribute__((ext_vector_type(4)));

__device__ __forceinline__ float bf2f(unsigned short u) {
    return __uint_as_float(((unsigned)u) << 16);
}
__device__ __forceinline__ unsigned short f2bf(float f) {
    unsigned u = __float_as_uint(f);
    unsigned r = (u + 0x7FFFu + ((u >> 16) & 1u)) >> 16;
    return (unsigned short)r;
}

#define GLOBAL_AS(p) ((const __attribute__((address_space(1))) unsigned int*)(p))
#define LDS_AS(p)    ((__attribute__((address_space(3))) unsigned int*)(p))

// m204 bijective XCD-chunk remap: physical bid -> logical idx.
__device__ __forceinline__ int xcd_remap(int bid, int nwg) {
    int xcd = bid & 7, pos = bid >> 3;
    int q = nwg >> 3, r = nwg & 7;
    int start = (xcd < r) ? xcd * (q + 1) : r * (q + 1) + (xcd - r) * q;
    return start + pos;
}

// ---------------------------------------------------------------------------
// Both weight tensors -> bf16 in one pass.
__global__ void convert_w_kernel(const float4* __restrict__ w1,
                                 ushort4* __restrict__ w1b, int n1,
                                 const float4* __restrict__ w2,
                                 ushort4* __restrict__ w2b, int n2) {
    int i = blockIdx.x * blockDim.x + threadIdx.x;
    int stride = gridDim.x * blockDim.x;
    int ntot = n1 + n2;
    for (; i < ntot; i += stride) {
        float4 v; ushort4 o;
        if (i < n1) v = w1[i]; else v = w2[i - n1];
        o.x = f2bf(v.x); o.y = f2bf(v.y); o.z = f2bf(v.z); o.w = f2bf(v.w);
        if (i < n1) w1b[i] = o; else w2b[i - n1] = o;
    }
}

// ---------------------------------------------------------------------------
// One wave per token: logits = x[t] . rw[e], softmax over 8, top-2, gates.
__global__ __launch_bounds__(256) void router_kernel(
    const float* __restrict__ x, const float* __restrict__ rw,
    int* __restrict__ topki, float* __restrict__ topkg,
    float* __restrict__ blkps)
{
    int wave = threadIdx.x >> 6;
    int lane = threadIdx.x & 63;
    int t = blockIdx.x * 4 + wave;
    const float* xt = x + (size_t)t * DIMD;

    float acc[NE];
#pragma unroll
    for (int e = 0; e < NE; e++) acc[e] = 0.f;
    for (int i = 0; i < DIMD / 64; i++) {
        float xv = xt[lane + 64 * i];
#pragma unroll
        for (int e = 0; e < NE; e++) acc[e] += xv * rw[e * DIMD + lane + 64 * i];
    }
#pragma unroll
    for (int off = 32; off > 0; off >>= 1) {
#pragma unroll
        for (int e = 0; e < NE; e++) acc[e] += __shfl_down(acc[e], off);
    }

    __shared__ float ps[4][NE];
    if (lane == 0) {
        float m = acc[0];
#pragma unroll
        for (int e = 1; e < NE; e++) m = fmaxf(m, acc[e]);
        float ex[NE], s = 0.f;
#pragma unroll
        for (int e = 0; e < NE; e++) { ex[e] = expf(acc[e] - m); s += ex[e]; }
        float inv = 1.f / s;
#pragma unroll
        for (int e = 0; e < NE; e++) ps[wave][e] = ex[e] * inv;

        int i0 = 0; float l0 = acc[0];
#pragma unroll
        for (int e = 1; e < NE; e++) if (acc[e] > l0) { l0 = acc[e]; i0 = e; }
        int i1 = -1; float l1 = -3.4e38f;
#pragma unroll
        for (int e = 0; e < NE; e++) if (e != i0 && acc[e] > l1) { l1 = acc[e]; i1 = e; }
        float e1 = expf(l1 - l0);
        float g0 = 1.f / (1.f + e1);
        float g1 = e1 * g0;
        topki[t * 2 + 0] = i0; topki[t * 2 + 1] = i1;
        topkg[t * 2 + 0] = g0; topkg[t * 2 + 1] = g1;
    }
    __syncthreads();
    if (threadIdx.x < NE) {
        float s = ps[0][threadIdx.x] + ps[1][threadIdx.x] + ps[2][threadIdx.x] + ps[3][threadIdx.x];
        blkps[blockIdx.x * NE + threadIdx.x] = s;
    }
}

// ---------------------------------------------------------------------------
// Single block: counts, offsets, cursors, 256-row tile prefix, aux loss.
__global__ __launch_bounds__(256) void finalize_kernel(
    const int* __restrict__ topki, const float* __restrict__ blkps,
    int* __restrict__ counts, int* __restrict__ offsets, int* __restrict__ cursors,
    int* __restrict__ tileoff, float* __restrict__ aux_out)
{
    __shared__ float psum[NE];
    __shared__ int cnt[NE];
    int tid = threadIdx.x;
    if (tid < NE) { psum[tid] = 0.f; cnt[tid] = 0; }
    __syncthreads();

    float lp[NE]; int lc[NE];
#pragma unroll
    for (int e = 0; e < NE; e++) { lp[e] = 0.f; lc[e] = 0; }
    const float4* bp4 = (const float4*)blkps;
    for (int i = tid; i < 2048 * NE / 4; i += 256) {
        float4 v = bp4[i];
        int eb = (4 * i) & 7;   // 0 or 4
        lp[eb + 0] += v.x; lp[eb + 1] += v.y; lp[eb + 2] += v.z; lp[eb + 3] += v.w;
    }
    const int4* ti4 = (const int4*)topki;
    for (int i = tid; i < TOKS * 2 / 4; i += 256) {
        int4 v = ti4[i];
        lc[v.x]++; lc[v.y]++; lc[v.z]++; lc[v.w]++;
    }
#pragma unroll
    for (int e = 0; e < NE; e++) { atomicAdd(&psum[e], lp[e]); atomicAdd(&cnt[e], lc[e]); }
    __syncthreads();

    if (tid == 0) {
        int off = 0, to = 0;
        for (int e = 0; e < NE; e++) {
            counts[e] = cnt[e];
            offsets[e] = off; cursors[e] = off;
            tileoff[e] = to;
            off += cnt[e];
            to += (cnt[e] + 255) >> 8;     // 256-row tiles
        }
        offsets[NE] = off; tileoff[NE] = to;
        float aux = 0.f;
        for (int e = 0; e < NE; e++)
            aux += ((float)cnt[e] / (float)(TOKS * 2)) * (psum[e] / (float)TOKS);
        aux_out[0] = (float)NE * aux;
    }
}

// ---------------------------------------------------------------------------
// Build packed per-expert (token, gate) lists + inverse map token->position.
__global__ __launch_bounds__(64) void fill_kernel(
    const int* __restrict__ topki, const float* __restrict__ topkg,
    int* __restrict__ cursors, int* __restrict__ atok, float* __restrict__ agate,
    int* __restrict__ posinv)
{
    int lane = threadIdx.x;
    int t = blockIdx.x * 64 + lane;
    unsigned long long below = (lane == 63) ? 0x7FFFFFFFFFFFFFFFull
                                            : ((1ull << lane) - 1ull);
#pragma unroll
    for (int k = 0; k < 2; k++) {
        int e = topki[t * 2 + k];
        float g = topkg[t * 2 + k];
        for (int ee = 0; ee < NE; ee++) {
            bool pred = (e == ee);
            unsigned long long mask = __ballot(pred ? 1 : 0);
            if (mask) {
                int leader = __ffsll((unsigned long long)mask) - 1;
                int base = 0;
                if (lane == leader) base = atomicAdd(&cursors[ee], (int)__popcll(mask));
                base = __shfl(base, leader);
                if (pred) {
                    int pos = base + (int)__popcll(mask & below);
                    atok[pos] = t;
                    agate[pos] = g;
                    posinv[t * 2 + k] = pos;
                }
            }
        }
    }
}

// ---------------------------------------------------------------------------
// Gather x rows into packed assignment order, fp32 -> bf16.
__global__ __launch_bounds__(256) void gather_x_kernel(
    const float* __restrict__ x, const int* __restrict__ atok,
    ushort* __restrict__ Xg)
{
    int r = blockIdx.x;
    int tid = threadIdx.x;
    int tok = atok[r];
    float4 v = ((const float4*)(x + (size_t)tok * DIMD))[tid];
    ushort4 o;
    o.x = f2bf(v.x); o.y = f2bf(v.y); o.z = f2bf(v.z); o.w = f2bf(v.w);
    ((ushort4*)(Xg + (size_t)r * DIMD))[tid] = o;
}

// ===========================================================================
// 256x256 8-phase GEMM core (template over K-stride LD and K-tiles NT).
// LDS chunks identical to R6: chunk = 16 rows x 32 k (1 KB); A chunks 0..31
// (row-subtile s, khalf kk -> s*2+kk), B chunks 32..63. Half-tiles:
// hf0=A rows 0-127 (chunks 0-15), hf1=A rows 128-255 (16-31),
// hf2=B cols 0-127 (32-47), hf3=B cols 128-255 (48-63).
// ===========================================================================
template<int LD, int NT>
__device__ __forceinline__ void gemm8ph(
    const ushort* __restrict__ gApanel, const ushort* __restrict__ gBpanel,
    ushort (&lds)[2][64][512], floatx4 (&acc)[8][4],
    int lane, int wave, int wr, int wc, int l15, int quad)
{
    const bf16x8* C0 = (const bf16x8*)&lds[0][0][0];
    const bf16x8* C1 = (const bf16x8*)&lds[1][0][0];

    // Stage one half-tile of K-tile u into buffer bsel. Wave stages chunks
    // (2*wave, 2*wave+1) of the half: rows (hf&1)*128 + wave*16 + l15,
    // k-cols u*64 + {0,32} + quad*8. Linear LDS dst (global_load_lds rule).
    auto stage_half = [&](int bsel, int hf, int u) {
        const ushort* panel = (hf & 2) ? gBpanel : gApanel;
        int rbase = (hf & 1) * 128 + wave * 16 + l15;
        const ushort* s0 = panel + (size_t)rbase * LD + u * 64 + quad * 8;
        __builtin_amdgcn_global_load_lds(GLOBAL_AS(s0),
            LDS_AS(&lds[bsel][hf * 16 + wave * 2 + 0][0]), 16, 0, 0);
        __builtin_amdgcn_global_load_lds(GLOBAL_AS(s0 + 32),
            LDS_AS(&lds[bsel][hf * 16 + wave * 2 + 1][0]), 16, 0, 0);
    };

#pragma unroll
    for (int i = 0; i < 8; i++)
#pragma unroll
        for (int j = 0; j < 4; j++) acc[i][j] = (floatx4){0.f, 0.f, 0.f, 0.f};

    bf16x8 af[4][2], bf[2][2];

    // Phase: quadrant (MH,NH); optionally (re)load a/b frags; optionally
    // stage one half; barrier; lgkmcnt(0); 16 MFMA; optional group-end wait.
#define PH(CB, MH, NH, RA, RB, DOSTAGE, SB, SHF, SU, DOWAIT, DEEP)            \
    {                                                                          \
        if (RA) {                                                              \
            _Pragma("unroll") for (int mi = 0; mi < 4; mi++) {                 \
                af[mi][0] = CB[((wr * 8 + (MH)*4 + mi) * 2 + 0) * 64 + lane];  \
                af[mi][1] = CB[((wr * 8 + (MH)*4 + mi) * 2 + 1) * 64 + lane];  \
            }                                                                  \
        }                                                                      \
        if (RB) {                                                              \
            _Pragma("unroll") for (int nj = 0; nj < 2; nj++) {                 \
                bf[nj][0] = CB[(32 + (wc * 4 + (NH)*2 + nj) * 2 + 0) * 64 + lane]; \
                bf[nj][1] = CB[(32 + (wc * 4 + (NH)*2 + nj) * 2 + 1) * 64 + lane]; \
            }                                                                  \
        }                                                                      \
        if (DOSTAGE) stage_half(SB, SHF, SU);                                  \
        __builtin_amdgcn_s_barrier();                                          \
        asm volatile("s_waitcnt lgkmcnt(0)" ::: "memory");                     \
        __builtin_amdgcn_sched_barrier(0);                                     \
        __builtin_amdgcn_s_setprio(1);                                         \
        _Pragma("unroll") for (int mi = 0; mi < 4; mi++)                       \
            _Pragma("unroll") for (int nj = 0; nj < 2; nj++)                   \
                _Pragma("unroll") for (int kk = 0; kk < 2; kk++)               \
                    acc[(MH)*4 + mi][(NH)*2 + nj] =                            \
                        __builtin_amdgcn_mfma_f32_16x16x32_bf16(               \
                            af[mi][kk], bf[nj][kk],                            \
                            acc[(MH)*4 + mi][(NH)*2 + nj], 0, 0, 0);           \
        __builtin_amdgcn_s_setprio(0);                                         \
        if (DOWAIT) {                                                          \
            if (DEEP) asm volatile("s_waitcnt vmcnt(0)" ::: "memory");         \
            else      asm volatile("s_waitcnt vmcnt(4)" ::: "memory");         \
        }                                                                      \
        __builtin_amdgcn_s_barrier();                                          \
    }

    // Prologue: tile0 (4 halves) + Ah0(1), Bh1(1); drain to tile0-complete.
    stage_half(0, 0, 0);   // Ah0(0)
    stage_half(0, 2, 0);   // Bh0(0)
    stage_half(0, 3, 0);   // Bh1(0)
    stage_half(0, 1, 0);   // Ah1(0)
    stage_half(1, 0, 1);   // Ah0(1)
    stage_half(1, 3, 1);   // Bh1(1)
    asm volatile("s_waitcnt vmcnt(4)" ::: "memory");
    __builtin_amdgcn_s_barrier();

    for (int u = 0; u < NT; u += 2) {
        // ---- K-tile u (buf0) ----
        PH(C0, 0, 0, 1, 1, (u + 1 < NT), 1, 1, u + 1, 0, 0);  // p1 +Ah1(u+1)
        PH(C0, 0, 1, 0, 1, (u + 1 < NT), 1, 2, u + 1, 0, 0);  // p2 +Bh0(u+1)
        PH(C0, 1, 1, 1, 0, (u + 2 < NT), 0, 0, u + 2, 0, 0);  // p3 +Ah0(u+2)
        PH(C0, 1, 0, 0, 1, (u + 2 < NT), 0, 3, u + 2, 1, (u + 2 >= NT)); // p4 +Bh1(u+2), wait
        // ---- K-tile u+1 (buf1) ----
        PH(C1, 0, 0, 1, 1, (u + 2 < NT), 0, 1, u + 2, 0, 0);  // p1 +Ah1(u+2)
        PH(C1, 0, 1, 0, 1, (u + 2 < NT), 0, 2, u + 2, 0, 0);  // p2 +Bh0(u+2)
        PH(C1, 1, 1, 1, 0, (u + 3 < NT), 1, 0, u + 3, 0, 0);  // p3 +Ah0(u+3)
        PH(C1, 1, 0, 0, 1, (u + 3 < NT), 1, 3, u + 3, 1, (u + 3 >= NT)); // p4 +Bh1(u+3), wait
    }
#undef PH
}

// ---------------------------------------------------------------------------
// Phase 1: H = gelu(Xg @ w1b[e]^T + b1[e]),  M=sum cnt, N=2048, K=1024.
__global__ __launch_bounds__(512, 2) void phase1_kernel(
    const ushort* __restrict__ Xg, const ushort* __restrict__ w1b,
    const float* __restrict__ b1,
    const int* __restrict__ counts, const int* __restrict__ offsets,
    const int* __restrict__ tileoff, unsigned short* __restrict__ Hbuf)
{
    const int NCOLT = HID / 256;   // 8 col tiles
    int total = tileoff[NE] * NCOLT;
    int idx = xcd_remap((int)blockIdx.x, (int)gridDim.x);
    if (idx >= total) return;
    int ct = idx & (NCOLT - 1);
    int rowt = idx / NCOLT;
    int e = 0;
    while (rowt >= tileoff[e + 1]) e++;
    int row0 = (rowt - tileoff[e]) * 256;
    int cnt = counts[e];
    int base = offsets[e];
    int colbase = ct * 256;

    __shared__ ushort lds[2][64][512];   // 128 KiB

    int tid = threadIdx.x;
    int lane = tid & 63;
    int wave = tid >> 6;
    int wr = wave >> 2, wc = wave & 3;
    int l15 = lane & 15, quad = lane >> 4;

    const ushort* gApanel = Xg + (size_t)(base + row0) * DIMD;
    const ushort* gBpanel = w1b + (size_t)e * HID * DIMD + (size_t)colbase * DIMD;

    floatx4 acc[8][4];
    gemm8ph<DIMD, DIMD / 64>(gApanel, gBpanel, lds, acc, lane, wave, wr, wc, l15, quad);

    // epilogue: bias + exact GELU, bf16 store. C/D: col=lane&15, row=quad*4+reg
    float b1v[4];
#pragma unroll
    for (int j = 0; j < 4; j++)
        b1v[j] = b1[e * HID + colbase + 64 * wc + 16 * j + l15];
#pragma unroll
    for (int i = 0; i < 8; i++) {
#pragma unroll
        for (int rr = 0; rr < 4; rr++) {
            int pr = row0 + 128 * wr + 16 * i + quad * 4 + rr;
            if (pr < cnt) {
                size_t hrow = (size_t)(base + pr) * HID;
#pragma unroll
                for (int j = 0; j < 4; j++) {
                    int col = colbase + 64 * wc + 16 * j + l15;
                    float v = acc[i][j][rr] + b1v[j];
                    v = 0.5f * v * (1.f + erff(v * 0.70710678118654752f));
                    Hbuf[hrow + col] = f2bf(v);
                }
            }
        }
    }
}

// ---------------------------------------------------------------------------
// Phase 2: Y = H @ w2b[e]^T,  M=sum cnt, N=1024, K=2048.
__global__ __launch_bounds__(512, 2) void phase2_kernel(
    const ushort* __restrict__ Hbuf, const ushort* __restrict__ w2b,
    const int* __restrict__ counts, const int* __restrict__ offsets,
    const int* __restrict__ tileoff, ushort* __restrict__ Y)
{
    const int NCOLT = DIMD / 256;  // 4 col tiles
    int total = tileoff[NE] * NCOLT;
    int idx = xcd_remap((int)blockIdx.x, (int)gridDim.x);
    if (idx >= total) return;
    int ct = idx & (NCOLT - 1);
    int rowt = idx / NCOLT;
    int e = 0;
    while (rowt >= tileoff[e + 1]) e++;
    int row0 = (rowt - tileoff[e]) * 256;
    int cnt = counts[e];
    int base = offsets[e];
    int colbase = ct * 256;

    __shared__ ushort lds[2][64][512];   // 128 KiB

    int tid = threadIdx.x;
    int lane = tid & 63;
    int wave = tid >> 6;
    int wr = wave >> 2, wc = wave & 3;
    int l15 = lane & 15, quad = lane >> 4;

    const ushort* gApanel = Hbuf + (size_t)(base + row0) * HID;
    const ushort* gBpanel = w2b + (size_t)e * DIMD * HID + (size_t)colbase * HID;

    floatx4 acc[8][4];
    gemm8ph<HID, HID / 64>(gApanel, gBpanel, lds, acc, lane, wave, wr, wc, l15, quad);

    // epilogue: plain bf16 store (bias+gate applied in combine)
#pragma unroll
    for (int i = 0; i < 8; i++) {
#pragma unroll
        for (int rr = 0; rr < 4; rr++) {
            int pr = row0 + 128 * wr + 16 * i + quad * 4 + rr;
            if (pr < cnt) {
                size_t yrow = (size_t)(base + pr) * DIMD;
#pragma unroll
                for (int j = 0; j < 4; j++) {
                    int col = colbase + 64 * wc + 16 * j + l15;
                    Y[yrow + col] = f2bf(acc[i][j][rr]);
                }
            }
        }
    }
}

// ---------------------------------------------------------------------------
// Combine: out[t,:] = g0*(Y[p0,:]+b2[e0,:]) + g1*(Y[p1,:]+b2[e1,:]).
__global__ __launch_bounds__(256) void combine_kernel(
    const ushort* __restrict__ Y, const float* __restrict__ b2,
    const int* __restrict__ topki, const float* __restrict__ topkg,
    const int* __restrict__ posinv, float* __restrict__ out)
{
    int wave = threadIdx.x >> 6;
    int lane = threadIdx.x & 63;
    int t = blockIdx.x * 4 + wave;
    int e0 = topki[t * 2 + 0], e1 = topki[t * 2 + 1];
    float g0 = topkg[t * 2 + 0], g1 = topkg[t * 2 + 1];
    int p0 = posinv[t * 2 + 0], p1 = posinv[t * 2 + 1];

    const ushort4* y0 = (const ushort4*)(Y + (size_t)p0 * DIMD);
    const ushort4* y1 = (const ushort4*)(Y + (size_t)p1 * DIMD);
    const float4* b20 = (const float4*)(b2 + (size_t)e0 * DIMD);
    const float4* b21 = (const float4*)(b2 + (size_t)e1 * DIMD);
    float4* o4 = (float4*)(out + (size_t)t * DIMD);

#pragma unroll
    for (int c = 0; c < DIMD / 4 / 64; c++) {   // 4 iterations
        int i = lane + 64 * c;
        ushort4 a = y0[i], b = y1[i];
        float4 ba = b20[i], bb = b21[i];
        float4 r;
        r.x = g0 * (bf2f(a.x) + ba.x) + g1 * (bf2f(b.x) + bb.x);
        r.y = g0 * (bf2f(a.y) + ba.y) + g1 * (bf2f(b.y) + bb.y);
        r.z = g0 * (bf2f(a.z) + ba.z) + g1 * (bf2f(b.z) + bb.z);
        r.w = g0 * (bf2f(a.w) + ba.w) + g1 * (bf2f(b.w) + bb.w);
        o4[i] = r;
    }
}

// ---------------------------------------------------------------------------
extern "C" void kernel_launch(void* const* d_in, const int* in_sizes, int n_in,
                              void* d_out, int out_size, void* d_ws, size_t ws_size,
                              hipStream_t stream) {
    const float* x  = (const float*)d_in[0];
    const float* rw = (const float*)d_in[1];
    const float* w1 = (const float*)d_in[2];
    const float* b1 = (const float*)d_in[3];
    const float* w2 = (const float*)d_in[4];
    const float* b2 = (const float*)d_in[5];
    float* out = (float*)d_out;

    char* ws = (char*)d_ws;
    int*   counts  = (int*)(ws + OFF_COUNTS);
    int*   offsets = (int*)(ws + OFF_OFFSETS);
    int*   cursors = (int*)(ws + OFF_CURSORS);
    int*   tileoff = (int*)(ws + OFF_TILEOFF);
    int*   topki   = (int*)(ws + OFF_TOPKI);
    float* topkg   = (float*)(ws + OFF_TOPKG);
    float* blkps   = (float*)(ws + OFF_BLKPS);
    int*   atok    = (int*)(ws + OFF_ATOK);
    float* agate   = (float*)(ws + OFF_AGATE);
    int*   posinv  = (int*)(ws + OFF_PINV);
    ushort* Xg     = (ushort*)(ws + OFF_XG);
    ushort* w1b    = (ushort*)(ws + OFF_W1B);
    ushort* w2b    = (ushort*)(ws + OFF_W2B);
    ushort* Hbuf   = (ushort*)(ws + OFF_H);
    ushort* Y      = (ushort*)(ws + OFF_Y);

    // weight conversions (independent of routing), one pass
    convert_w_kernel<<<8192, 256, 0, stream>>>(
        (const float4*)w1, (ushort4*)w1b, NE * HID * DIMD / 4,
        (const float4*)w2, (ushort4*)w2b, NE * DIMD * HID / 4);

    router_kernel<<<TOKS / 4, 256, 0, stream>>>(x, rw, topki, topkg, blkps);
    finalize_kernel<<<1, 256, 0, stream>>>(topki, blkps, counts, offsets, cursors,
                                           tileoff, out + (size_t)TOKS * DIMD);
    fill_kernel<<<TOKS / 64, 64, 0, stream>>>(topki, topkg, cursors, atok, agate,
                                              posinv);
    gather_x_kernel<<<TOKS * 2, 256, 0, stream>>>(x, atok, Xg);

    // worst-case 256-row tiles: sum_e ceil(cnt_e/256) <= 16384/256 + 7 = 71
    phase1_kernel<<<71 * (HID / 256), 512, 0, stream>>>(
        Xg, w1b, b1, counts, offsets, tileoff, Hbuf);
    phase2_kernel<<<71 * (DIMD / 256), 512, 0, stream>>>(
        Hbuf, w2b, counts, offsets, tileoff, Y);
    combine_kernel<<<TOKS / 4, 256, 0, stream>>>(Y, b2, topki, topkg, posinv, out);
}

// Round 4
// 582.221 us; speedup vs baseline: 1.1736x; 1.0156x over previous
//
#include <hip/hip_runtime.h>

// ============================================================================
// MoE block (top-2 of 8 experts), T=8192 tokens, d=1024, h=2048.
// R8: 256x256 8-phase GEMMs, compiler-scheduled LDS drain.
//  - REMOVED the forced lgkmcnt(0)+sched_barrier(0) before MFMA (R7's
//    mistake): ds_reads are compiler-visible intrinsics, so the waitcnt pass
//    emits counted lgkmcnt per-MFMA and the LDS drain overlaps the MFMA
//    cluster (m97/m201 mechanism). R7 serialized ~600cy LDS + ~620cy MFMA
//    per phase; this overlaps them.
//  - Quadrant-aligned stage units (A0/A1/B0/B1 match MH/NH read stripes):
//    each unit staged in the phase AFTER its last read (>=1 barrier apart),
//    fixing R7's same-phase WAR race. One s_waitcnt vmcnt(6) per K-tile
//    (2 loads/wave/unit x 3 units in flight), vmcnt(0) only in tail groups.
//    Ledger: tile u, p1 stages B0(u+1); p2 A0(u+2); p3 B1(u+2); p4 A1(u+2)
//    + vmcnt(6) -> completes all of tile u+1, leaves {A0,B1,A1}(u+2).
//  - setprio(1) around MFMA cluster (T5), XCD-bijective remap (m204) kept.
// ============================================================================

#define TOKS 8192
#define DIMD 1024
#define HID  2048
#define NE   8

#define OFF_COUNTS   0
#define OFF_OFFSETS  64
#define OFF_CURSORS  128
#define OFF_TILEOFF  192
#define OFF_TOPKI    256
#define OFF_TOPKG    (OFF_TOPKI + TOKS*2*4)
#define OFF_BLKPS    (OFF_TOPKG + TOKS*2*4)
#define OFF_ATOK     (OFF_BLKPS + 2048*NE*4)
#define OFF_AGATE    (OFF_ATOK + TOKS*2*4)
#define OFF_PINV     (OFF_AGATE + TOKS*2*4)
#define OFF_XG       (1u << 20)
#define XG_ROWS      (TOKS*2 + 256)
#define OFF_W1B      (OFF_XG  + (size_t)XG_ROWS * DIMD * 2)
#define OFF_W2B      (OFF_W1B + (size_t)NE * HID * DIMD * 2)
#define OFF_H        (OFF_W2B + (size_t)NE * DIMD * HID * 2)
#define OFF_Y        (OFF_H   + (size_t)XG_ROWS * HID * 2)

typedef __bf16 bf16x8 __attribute__((ext_vector_type(8)));
typedef float  floatx4 __attribute__((ext_vector_type(4)));

__device__ __forceinline__ float bf2f(unsigned short u) {
    return __uint_as_float(((unsigned)u) << 16);
}
__device__ __forceinline__ unsigned short f2bf(float f) {
    unsigned u = __float_as_uint(f);
    unsigned r = (u + 0x7FFFu + ((u >> 16) & 1u)) >> 16;
    return (unsigned short)r;
}

#define GLOBAL_AS(p) ((const __attribute__((address_space(1))) unsigned int*)(p))
#define LDS_AS(p)    ((__attribute__((address_space(3))) unsigned int*)(p))
#define CFENCE()     asm volatile("" ::: "memory")

// m204 bijective XCD-chunk remap: physical bid -> logical idx.
__device__ __forceinline__ int xcd_remap(int bid, int nwg) {
    int xcd = bid & 7, pos = bid >> 3;
    int q = nwg >> 3, r = nwg & 7;
    int start = (xcd < r) ? xcd * (q + 1) : r * (q + 1) + (xcd - r) * q;
    return start + pos;
}

// ---------------------------------------------------------------------------
// Both weight tensors -> bf16 in one pass.
__global__ void convert_w_kernel(const float4* __restrict__ w1,
                                 ushort4* __restrict__ w1b, int n1,
                                 const float4* __restrict__ w2,
                                 ushort4* __restrict__ w2b, int n2) {
    int i = blockIdx.x * blockDim.x + threadIdx.x;
    int stride = gridDim.x * blockDim.x;
    int ntot = n1 + n2;
    for (; i < ntot; i += stride) {
        float4 v; ushort4 o;
        if (i < n1) v = w1[i]; else v = w2[i - n1];
        o.x = f2bf(v.x); o.y = f2bf(v.y); o.z = f2bf(v.z); o.w = f2bf(v.w);
        if (i < n1) w1b[i] = o; else w2b[i - n1] = o;
    }
}

// ---------------------------------------------------------------------------
// One wave per token: logits = x[t] . rw[e], softmax over 8, top-2, gates.
__global__ __launch_bounds__(256) void router_kernel(
    const float* __restrict__ x, const float* __restrict__ rw,
    int* __restrict__ topki, float* __restrict__ topkg,
    float* __restrict__ blkps)
{
    int wave = threadIdx.x >> 6;
    int lane = threadIdx.x & 63;
    int t = blockIdx.x * 4 + wave;
    const float* xt = x + (size_t)t * DIMD;

    float acc[NE];
#pragma unroll
    for (int e = 0; e < NE; e++) acc[e] = 0.f;
    for (int i = 0; i < DIMD / 64; i++) {
        float xv = xt[lane + 64 * i];
#pragma unroll
        for (int e = 0; e < NE; e++) acc[e] += xv * rw[e * DIMD + lane + 64 * i];
    }
#pragma unroll
    for (int off = 32; off > 0; off >>= 1) {
#pragma unroll
        for (int e = 0; e < NE; e++) acc[e] += __shfl_down(acc[e], off);
    }

    __shared__ float ps[4][NE];
    if (lane == 0) {
        float m = acc[0];
#pragma unroll
        for (int e = 1; e < NE; e++) m = fmaxf(m, acc[e]);
        float ex[NE], s = 0.f;
#pragma unroll
        for (int e = 0; e < NE; e++) { ex[e] = expf(acc[e] - m); s += ex[e]; }
        float inv = 1.f / s;
#pragma unroll
        for (int e = 0; e < NE; e++) ps[wave][e] = ex[e] * inv;

        int i0 = 0; float l0 = acc[0];
#pragma unroll
        for (int e = 1; e < NE; e++) if (acc[e] > l0) { l0 = acc[e]; i0 = e; }
        int i1 = -1; float l1 = -3.4e38f;
#pragma unroll
        for (int e = 0; e < NE; e++) if (e != i0 && acc[e] > l1) { l1 = acc[e]; i1 = e; }
        float e1 = expf(l1 - l0);
        float g0 = 1.f / (1.f + e1);
        float g1 = e1 * g0;
        topki[t * 2 + 0] = i0; topki[t * 2 + 1] = i1;
        topkg[t * 2 + 0] = g0; topkg[t * 2 + 1] = g1;
    }
    __syncthreads();
    if (threadIdx.x < NE) {
        float s = ps[0][threadIdx.x] + ps[1][threadIdx.x] + ps[2][threadIdx.x] + ps[3][threadIdx.x];
        blkps[blockIdx.x * NE + threadIdx.x] = s;
    }
}

// ---------------------------------------------------------------------------
// Single block: counts, offsets, cursors, 256-row tile prefix, aux loss.
__global__ __launch_bounds__(256) void finalize_kernel(
    const int* __restrict__ topki, const float* __restrict__ blkps,
    int* __restrict__ counts, int* __restrict__ offsets, int* __restrict__ cursors,
    int* __restrict__ tileoff, float* __restrict__ aux_out)
{
    __shared__ float psum[NE];
    __shared__ int cnt[NE];
    int tid = threadIdx.x;
    if (tid < NE) { psum[tid] = 0.f; cnt[tid] = 0; }
    __syncthreads();

    float lp[NE]; int lc[NE];
#pragma unroll
    for (int e = 0; e < NE; e++) { lp[e] = 0.f; lc[e] = 0; }
    const float4* bp4 = (const float4*)blkps;
    for (int i = tid; i < 2048 * NE / 4; i += 256) {
        float4 v = bp4[i];
        int eb = (4 * i) & 7;   // 0 or 4
        lp[eb + 0] += v.x; lp[eb + 1] += v.y; lp[eb + 2] += v.z; lp[eb + 3] += v.w;
    }
    const int4* ti4 = (const int4*)topki;
    for (int i = tid; i < TOKS * 2 / 4; i += 256) {
        int4 v = ti4[i];
        lc[v.x]++; lc[v.y]++; lc[v.z]++; lc[v.w]++;
    }
#pragma unroll
    for (int e = 0; e < NE; e++) { atomicAdd(&psum[e], lp[e]); atomicAdd(&cnt[e], lc[e]); }
    __syncthreads();

    if (tid == 0) {
        int off = 0, to = 0;
        for (int e = 0; e < NE; e++) {
            counts[e] = cnt[e];
            offsets[e] = off; cursors[e] = off;
            tileoff[e] = to;
            off += cnt[e];
            to += (cnt[e] + 255) >> 8;     // 256-row tiles
        }
        offsets[NE] = off; tileoff[NE] = to;
        float aux = 0.f;
        for (int e = 0; e < NE; e++)
            aux += ((float)cnt[e] / (float)(TOKS * 2)) * (psum[e] / (float)TOKS);
        aux_out[0] = (float)NE * aux;
    }
}

// ---------------------------------------------------------------------------
// Build packed per-expert (token, gate) lists + inverse map token->position.
__global__ __launch_bounds__(64) void fill_kernel(
    const int* __restrict__ topki, const float* __restrict__ topkg,
    int* __restrict__ cursors, int* __restrict__ atok, float* __restrict__ agate,
    int* __restrict__ posinv)
{
    int lane = threadIdx.x;
    int t = blockIdx.x * 64 + lane;
    unsigned long long below = (lane == 63) ? 0x7FFFFFFFFFFFFFFFull
                                            : ((1ull << lane) - 1ull);
#pragma unroll
    for (int k = 0; k < 2; k++) {
        int e = topki[t * 2 + k];
        float g = topkg[t * 2 + k];
        for (int ee = 0; ee < NE; ee++) {
            bool pred = (e == ee);
            unsigned long long mask = __ballot(pred ? 1 : 0);
            if (mask) {
                int leader = __ffsll((unsigned long long)mask) - 1;
                int base = 0;
                if (lane == leader) base = atomicAdd(&cursors[ee], (int)__popcll(mask));
                base = __shfl(base, leader);
                if (pred) {
                    int pos = base + (int)__popcll(mask & below);
                    atok[pos] = t;
                    agate[pos] = g;
                    posinv[t * 2 + k] = pos;
                }
            }
        }
    }
}

// ---------------------------------------------------------------------------
// Gather x rows into packed assignment order, fp32 -> bf16.
__global__ __launch_bounds__(256) void gather_x_kernel(
    const float* __restrict__ x, const int* __restrict__ atok,
    ushort* __restrict__ Xg)
{
    int r = blockIdx.x;
    int tid = threadIdx.x;
    int tok = atok[r];
    float4 v = ((const float4*)(x + (size_t)tok * DIMD))[tid];
    ushort4 o;
    o.x = f2bf(v.x); o.y = f2bf(v.y); o.z = f2bf(v.z); o.w = f2bf(v.w);
    ((ushort4*)(Xg + (size_t)r * DIMD))[tid] = o;
}

// ===========================================================================
// 256x256 8-phase GEMM core. LDS chunk = 16 rows x 32 k (1 KB); A chunks
// 0..31 (row-subtile s, khalf kk -> s*2+kk), B chunks 32..63.
// Stage units (quadrant-aligned):
//   A0 = row-subtiles {0-3,8-11}   (MH=0 stripe: rows 0-63 & 128-191)
//   A1 = row-subtiles {4-7,12-15}  (MH=1 stripe)
//   B0 = col-subtiles s'%4 in {0,1} (NH=0 frags)
//   B1 = col-subtiles s'%4 in {2,3} (NH=1 frags)
// Per tile u: p1(MH0,NH0) reads A0,B0; p2(MH0,NH1) reads B1; p3(MH1,NH1)
// reads A1; p4(MH1,NH0) re-reads B0. Unit dead-after: A0:p1 B1:p2 A1:p3
// B0:p4 -> staged one phase later (one barrier of separation).
// ===========================================================================
template<int LD, int NT>
__device__ __forceinline__ void gemm8ph(
    const ushort* __restrict__ gApanel, const ushort* __restrict__ gBpanel,
    ushort (&lds)[2][64][512], floatx4 (&acc)[8][4],
    int lane, int wave, int wr, int wc, int l15, int quad)
{
    const bf16x8* C0 = (const bf16x8*)&lds[0][0][0];
    const bf16x8* C1 = (const bf16x8*)&lds[1][0][0];

    // Stage unit (0=A0,1=A1,2=B0,3=B1) of K-tile u into buffer bsel.
    // Each wave stages one 16-row subtile = 2 chunks (2 global_load_lds).
    auto stage_unit = [&](int bsel, int unit, int u) {
        int s, chunk;
        const ushort* panel;
        if (unit < 2) {
            s = (wave < 4 ? wave : wave + 4) + unit * 4;
            chunk = s * 2;
            panel = gApanel;
        } else {
            s = (wave & 1) + ((wave >> 1) * 4) + ((unit == 3) ? 2 : 0);
            chunk = 32 + s * 2;
            panel = gBpanel;
        }
        const ushort* s0 = panel + (size_t)(s * 16 + l15) * LD + u * 64 + quad * 8;
        __builtin_amdgcn_global_load_lds(GLOBAL_AS(s0),
            LDS_AS(&lds[bsel][chunk + 0][0]), 16, 0, 0);
        __builtin_amdgcn_global_load_lds(GLOBAL_AS(s0 + 32),
            LDS_AS(&lds[bsel][chunk + 1][0]), 16, 0, 0);
    };

#pragma unroll
    for (int i = 0; i < 8; i++)
#pragma unroll
        for (int j = 0; j < 4; j++) acc[i][j] = (floatx4){0.f, 0.f, 0.f, 0.f};

    bf16x8 af[4][2], bf[2][2];

    // Phase: read frags (RB first so the first MFMA's wait is short), stage
    // one unit, barrier, MFMA cluster (compiler emits counted lgkmcnt per
    // use -> LDS drain overlaps MFMA), optional counted vmcnt, barrier.
#define PH(CB, MH, NH, RA, RB, DOSTAGE, SB, SUNIT, SU, DOWAIT, DEEP)          \
    {                                                                          \
        if (RB) {                                                              \
            _Pragma("unroll") for (int nj = 0; nj < 2; nj++) {                 \
                bf[nj][0] = CB[(32 + (wc * 4 + (NH)*2 + nj) * 2 + 0) * 64 + lane]; \
                bf[nj][1] = CB[(32 + (wc * 4 + (NH)*2 + nj) * 2 + 1) * 64 + lane]; \
            }                                                                  \
        }                                                                      \
        if (RA) {                                                              \
            _Pragma("unroll") for (int mi = 0; mi < 4; mi++) {                 \
                af[mi][0] = CB[((wr * 8 + (MH)*4 + mi) * 2 + 0) * 64 + lane];  \
                af[mi][1] = CB[((wr * 8 + (MH)*4 + mi) * 2 + 1) * 64 + lane];  \
            }                                                                  \
        }                                                                      \
        if (DOSTAGE) stage_unit(SB, SUNIT, SU);                                \
        CFENCE();                                                              \
        __builtin_amdgcn_s_barrier();                                          \
        CFENCE();                                                              \
        __builtin_amdgcn_s_setprio(1);                                         \
        _Pragma("unroll") for (int mi = 0; mi < 4; mi++)                       \
            _Pragma("unroll") for (int nj = 0; nj < 2; nj++)                   \
                _Pragma("unroll") for (int kk = 0; kk < 2; kk++)               \
                    acc[(MH)*4 + mi][(NH)*2 + nj] =                            \
                        __builtin_amdgcn_mfma_f32_16x16x32_bf16(               \
                            af[mi][kk], bf[nj][kk],                            \
                            acc[(MH)*4 + mi][(NH)*2 + nj], 0, 0, 0);           \
        __builtin_amdgcn_s_setprio(0);                                         \
        if (DOWAIT) {                                                          \
            if (DEEP) asm volatile("s_waitcnt vmcnt(0)" ::: "memory");         \
            else      asm volatile("s_waitcnt vmcnt(6)" ::: "memory");         \
        }                                                                      \
        CFENCE();                                                              \
        __builtin_amdgcn_s_barrier();                                          \
        CFENCE();                                                              \
    }

    // Prologue: tile0's 4 units + {A0,B1,A1}(1); wait vmcnt(6) -> tile0
    // complete, 6 in flight (steady invariant; B0(1) staged at tile0 p1).
    stage_unit(0, 0, 0);   // A0(0)
    stage_unit(0, 2, 0);   // B0(0)
    stage_unit(0, 3, 0);   // B1(0)
    stage_unit(0, 1, 0);   // A1(0)
    stage_unit(1, 0, 1);   // A0(1)
    stage_unit(1, 3, 1);   // B1(1)
    stage_unit(1, 1, 1);   // A1(1)
    asm volatile("s_waitcnt vmcnt(6)" ::: "memory");
    CFENCE();
    __builtin_amdgcn_s_barrier();
    CFENCE();

    for (int u = 0; u < NT; u += 2) {
        // ---- K-tile u (buf0) ----
        PH(C0, 0, 0, 1, 1, (u + 1 < NT), 1, 2, u + 1, 0, 0);              // p1 +B0(u+1)
        PH(C0, 0, 1, 0, 1, (u + 2 < NT), 0, 0, u + 2, 0, 0);              // p2 +A0(u+2)
        PH(C0, 1, 1, 1, 0, (u + 2 < NT), 0, 3, u + 2, 0, 0);              // p3 +B1(u+2)
        PH(C0, 1, 0, 0, 1, (u + 2 < NT), 0, 1, u + 2, 1, (u + 2 >= NT));  // p4 +A1(u+2), wait
        // ---- K-tile u+1 (buf1) ----
        PH(C1, 0, 0, 1, 1, (u + 2 < NT), 0, 2, u + 2, 0, 0);              // p1 +B0(u+2)
        PH(C1, 0, 1, 0, 1, (u + 3 < NT), 1, 0, u + 3, 0, 0);              // p2 +A0(u+3)
        PH(C1, 1, 1, 1, 0, (u + 3 < NT), 1, 3, u + 3, 0, 0);              // p3 +B1(u+3)
        PH(C1, 1, 0, 0, 1, (u + 3 < NT), 1, 1, u + 3, 1, (u + 3 >= NT));  // p4 +A1(u+3), wait
    }
#undef PH
}

// ---------------------------------------------------------------------------
// Phase 1: H = gelu(Xg @ w1b[e]^T + b1[e]),  M=sum cnt, N=2048, K=1024.
__global__ __launch_bounds__(512, 2) void phase1_kernel(
    const ushort* __restrict__ Xg, const ushort* __restrict__ w1b,
    const float* __restrict__ b1,
    const int* __restrict__ counts, const int* __restrict__ offsets,
    const int* __restrict__ tileoff, unsigned short* __restrict__ Hbuf)
{
    const int NCOLT = HID / 256;   // 8 col tiles
    int total = tileoff[NE] * NCOLT;
    int idx = xcd_remap((int)blockIdx.x, (int)gridDim.x);
    if (idx >= total) return;
    int ct = idx & (NCOLT - 1);
    int rowt = idx / NCOLT;
    int e = 0;
    while (rowt >= tileoff[e + 1]) e++;
    int row0 = (rowt - tileoff[e]) * 256;
    int cnt = counts[e];
    int base = offsets[e];
    int colbase = ct * 256;

    __shared__ ushort lds[2][64][512];   // 128 KiB

    int tid = threadIdx.x;
    int lane = tid & 63;
    int wave = tid >> 6;
    int wr = wave >> 2, wc = wave & 3;
    int l15 = lane & 15, quad = lane >> 4;

    const ushort* gApanel = Xg + (size_t)(base + row0) * DIMD;
    const ushort* gBpanel = w1b + (size_t)e * HID * DIMD + (size_t)colbase * DIMD;

    floatx4 acc[8][4];
    gemm8ph<DIMD, DIMD / 64>(gApanel, gBpanel, lds, acc, lane, wave, wr, wc, l15, quad);

    // epilogue: bias + exact GELU, bf16 store. C/D: col=lane&15, row=quad*4+reg
    float b1v[4];
#pragma unroll
    for (int j = 0; j < 4; j++)
        b1v[j] = b1[e * HID + colbase + 64 * wc + 16 * j + l15];
#pragma unroll
    for (int i = 0; i < 8; i++) {
#pragma unroll
        for (int rr = 0; rr < 4; rr++) {
            int pr = row0 + 128 * wr + 16 * i + quad * 4 + rr;
            if (pr < cnt) {
                size_t hrow = (size_t)(base + pr) * HID;
#pragma unroll
                for (int j = 0; j < 4; j++) {
                    int col = colbase + 64 * wc + 16 * j + l15;
                    float v = acc[i][j][rr] + b1v[j];
                    v = 0.5f * v * (1.f + erff(v * 0.70710678118654752f));
                    Hbuf[hrow + col] = f2bf(v);
                }
            }
        }
    }
}

// ---------------------------------------------------------------------------
// Phase 2: Y = H @ w2b[e]^T,  M=sum cnt, N=1024, K=2048.
__global__ __launch_bounds__(512, 2) void phase2_kernel(
    const ushort* __restrict__ Hbuf, const ushort* __restrict__ w2b,
    const int* __restrict__ counts, const int* __restrict__ offsets,
    const int* __restrict__ tileoff, ushort* __restrict__ Y)
{
    const int NCOLT = DIMD / 256;  // 4 col tiles
    int total = tileoff[NE] * NCOLT;
    int idx = xcd_remap((int)blockIdx.x, (int)gridDim.x);
    if (idx >= total) return;
    int ct = idx & (NCOLT - 1);
    int rowt = idx / NCOLT;
    int e = 0;
    while (rowt >= tileoff[e + 1]) e++;
    int row0 = (rowt - tileoff[e]) * 256;
    int cnt = counts[e];
    int base = offsets[e];
    int colbase = ct * 256;

    __shared__ ushort lds[2][64][512];   // 128 KiB

    int tid = threadIdx.x;
    int lane = tid & 63;
    int wave = tid >> 6;
    int wr = wave >> 2, wc = wave & 3;
    int l15 = lane & 15, quad = lane >> 4;

    const ushort* gApanel = Hbuf + (size_t)(base + row0) * HID;
    const ushort* gBpanel = w2b + (size_t)e * DIMD * HID + (size_t)colbase * HID;

    floatx4 acc[8][4];
    gemm8ph<HID, HID / 64>(gApanel, gBpanel, lds, acc, lane, wave, wr, wc, l15, quad);

    // epilogue: plain bf16 store (bias+gate applied in combine)
#pragma unroll
    for (int i = 0; i < 8; i++) {
#pragma unroll
        for (int rr = 0; rr < 4; rr++) {
            int pr = row0 + 128 * wr + 16 * i + quad * 4 + rr;
            if (pr < cnt) {
                size_t yrow = (size_t)(base + pr) * DIMD;
#pragma unroll
                for (int j = 0; j < 4; j++) {
                    int col = colbase + 64 * wc + 16 * j + l15;
                    Y[yrow + col] = f2bf(acc[i][j][rr]);
                }
            }
        }
    }
}

// ---------------------------------------------------------------------------
// Combine: out[t,:] = g0*(Y[p0,:]+b2[e0,:]) + g1*(Y[p1,:]+b2[e1,:]).
__global__ __launch_bounds__(256) void combine_kernel(
    const ushort* __restrict__ Y, const float* __restrict__ b2,
    const int* __restrict__ topki, const float* __restrict__ topkg,
    const int* __restrict__ posinv, float* __restrict__ out)
{
    int wave = threadIdx.x >> 6;
    int lane = threadIdx.x & 63;
    int t = blockIdx.x * 4 + wave;
    int e0 = topki[t * 2 + 0], e1 = topki[t * 2 + 1];
    float g0 = topkg[t * 2 + 0], g1 = topkg[t * 2 + 1];
    int p0 = posinv[t * 2 + 0], p1 = posinv[t * 2 + 1];

    const ushort4* y0 = (const ushort4*)(Y + (size_t)p0 * DIMD);
    const ushort4* y1 = (const ushort4*)(Y + (size_t)p1 * DIMD);
    const float4* b20 = (const float4*)(b2 + (size_t)e0 * DIMD);
    const float4* b21 = (const float4*)(b2 + (size_t)e1 * DIMD);
    float4* o4 = (float4*)(out + (size_t)t * DIMD);

#pragma unroll
    for (int c = 0; c < DIMD / 4 / 64; c++) {   // 4 iterations
        int i = lane + 64 * c;
        ushort4 a = y0[i], b = y1[i];
        float4 ba = b20[i], bb = b21[i];
        float4 r;
        r.x = g0 * (bf2f(a.x) + ba.x) + g1 * (bf2f(b.x) + bb.x);
        r.y = g0 * (bf2f(a.y) + ba.y) + g1 * (bf2f(b.y) + bb.y);
        r.z = g0 * (bf2f(a.z) + ba.z) + g1 * (bf2f(b.z) + bb.z);
        r.w = g0 * (bf2f(a.w) + ba.w) + g1 * (bf2f(b.w) + bb.w);
        o4[i] = r;
    }
}

// ---------------------------------------------------------------------------
extern "C" void kernel_launch(void* const* d_in, const int* in_sizes, int n_in,
                              void* d_out, int out_size, void* d_ws, size_t ws_size,
                              hipStream_t stream) {
    const float* x  = (const float*)d_in[0];
    const float* rw = (const float*)d_in[1];
    const float* w1 = (const float*)d_in[2];
    const float* b1 = (const float*)d_in[3];
    const float* w2 = (const float*)d_in[4];
    const float* b2 = (const float*)d_in[5];
    float* out = (float*)d_out;

    char* ws = (char*)d_ws;
    int*   counts  = (int*)(ws + OFF_COUNTS);
    int*   offsets = (int*)(ws + OFF_OFFSETS);
    int*   cursors = (int*)(ws + OFF_CURSORS);
    int*   tileoff = (int*)(ws + OFF_TILEOFF);
    int*   topki   = (int*)(ws + OFF_TOPKI);
    float* topkg   = (float*)(ws + OFF_TOPKG);
    float* blkps   = (float*)(ws + OFF_BLKPS);
    int*   atok    = (int*)(ws + OFF_ATOK);
    float* agate   = (float*)(ws + OFF_AGATE);
    int*   posinv  = (int*)(ws + OFF_PINV);
    ushort* Xg     = (ushort*)(ws + OFF_XG);
    ushort* w1b    = (ushort*)(ws + OFF_W1B);
    ushort* w2b    = (ushort*)(ws + OFF_W2B);
    ushort* Hbuf   = (ushort*)(ws + OFF_H);
    ushort* Y      = (ushort*)(ws + OFF_Y);

    // weight conversions (independent of routing), one pass
    convert_w_kernel<<<8192, 256, 0, stream>>>(
        (const float4*)w1, (ushort4*)w1b, NE * HID * DIMD / 4,
        (const float4*)w2, (ushort4*)w2b, NE * DIMD * HID / 4);

    router_kernel<<<TOKS / 4, 256, 0, stream>>>(x, rw, topki, topkg, blkps);
    finalize_kernel<<<1, 256, 0, stream>>>(topki, blkps, counts, offsets, cursors,
                                           tileoff, out + (size_t)TOKS * DIMD);
    fill_kernel<<<TOKS / 64, 64, 0, stream>>>(topki, topkg, cursors, atok, agate,
                                              posinv);
    gather_x_kernel<<<TOKS * 2, 256, 0, stream>>>(x, atok, Xg);

    // worst-case 256-row tiles: sum_e ceil(cnt_e/256) <= 16384/256 + 7 = 71
    phase1_kernel<<<71 * (HID / 256), 512, 0, stream>>>(
        Xg, w1b, b1, counts, offsets, tileoff, Hbuf);
    phase2_kernel<<<71 * (DIMD / 256), 512, 0, stream>>>(
        Hbuf, w2b, counts, offsets, tileoff, Y);
    combine_kernel<<<TOKS / 4, 256, 0, stream>>>(Y, b2, topki, topkg, posinv, out);
}

// Round 5
// 580.343 us; speedup vs baseline: 1.1774x; 1.0032x over previous
//
#include <hip/hip_runtime.h>

// ============================================================================
// MoE block (top-2 of 8 experts), T=8192 tokens, d=1024, h=2048.
// R9: R8 geometry/ledger EXACTLY, minus the hidden vmcnt(0) drains.
//   Root cause found: asm with ":::memory" clobber (R7/R8 CFENCE + counted
//   waits) makes the AMDGPU waitcnt pass insert s_waitcnt vmcnt(0) lgkmcnt(0)
//   before the asm (it must assume the asm reads memory pending from
//   global_load_lds). So every phase drained to zero -> m218's "drain0"
//   variant, which explains R6~R7~R8 all at ~2100 cy/phase vs m201's 824.
//   Fix: bare counted waits (no clobber), raw s_barrier, sched_barrier(0)
//   guard after each barrier (zero-cost, prevents ds_read hoist above the
//   group-validity barrier).
// Ledger (unchanged from R8, HW-verified):
//   group u: p1 B0(u+1)->buf1 | p2 A0(u+2)->buf0 | p3 B1(u+2)->buf0 |
//            p4 A1(u+2)->buf0 + vmcnt(6)  => tile u+1 complete, 6 in flight
//   second half: p1' B0(u+2)->buf0 | p2' A0(u+3)->buf1 | p3' B1(u+3)->buf1 |
//            p4' A1(u+3)->buf1 + vmcnt(6) => tile u+2 complete.
//   All stages land in slots last read >=1 barrier earlier. Tails: vmcnt(0).
// ============================================================================

#define TOKS 8192
#define DIMD 1024
#define HID  2048
#define NE   8

#define OFF_COUNTS   0
#define OFF_OFFSETS  64
#define OFF_CURSORS  128
#define OFF_TILEOFF  192
#define OFF_TOPKI    256
#define OFF_TOPKG    (OFF_TOPKI + TOKS*2*4)
#define OFF_BLKPS    (OFF_TOPKG + TOKS*2*4)
#define OFF_ATOK     (OFF_BLKPS + 2048*NE*4)
#define OFF_AGATE    (OFF_ATOK + TOKS*2*4)
#define OFF_PINV     (OFF_AGATE + TOKS*2*4)
#define OFF_XG       (1u << 20)
#define XG_ROWS      (TOKS*2 + 256)
#define OFF_W1B      (OFF_XG  + (size_t)XG_ROWS * DIMD * 2)
#define OFF_W2B      (OFF_W1B + (size_t)NE * HID * DIMD * 2)
#define OFF_H        (OFF_W2B + (size_t)NE * DIMD * HID * 2)
#define OFF_Y        (OFF_H   + (size_t)XG_ROWS * HID * 2)

typedef __bf16 bf16x8 __attribute__((ext_vector_type(8)));
typedef float  floatx4 __attribute__((ext_vector_type(4)));

__device__ __forceinline__ float bf2f(unsigned short u) {
    return __uint_as_float(((unsigned)u) << 16);
}
__device__ __forceinline__ unsigned short f2bf(float f) {
    unsigned u = __float_as_uint(f);
    unsigned r = (u + 0x7FFFu + ((u >> 16) & 1u)) >> 16;
    return (unsigned short)r;
}

#define GLOBAL_AS(p) ((const __attribute__((address_space(1))) unsigned int*)(p))
#define LDS_AS(p)    ((__attribute__((address_space(3))) unsigned int*)(p))

// m204 bijective XCD-chunk remap: physical bid -> logical idx.
__device__ __forceinline__ int xcd_remap(int bid, int nwg) {
    int xcd = bid & 7, pos = bid >> 3;
    int q = nwg >> 3, r = nwg & 7;
    int start = (xcd < r) ? xcd * (q + 1) : r * (q + 1) + (xcd - r) * q;
    return start + pos;
}

// ---------------------------------------------------------------------------
// Both weight tensors -> bf16 in one pass.
__global__ void convert_w_kernel(const float4* __restrict__ w1,
                                 ushort4* __restrict__ w1b, int n1,
                                 const float4* __restrict__ w2,
                                 ushort4* __restrict__ w2b, int n2) {
    int i = blockIdx.x * blockDim.x + threadIdx.x;
    int stride = gridDim.x * blockDim.x;
    int ntot = n1 + n2;
    for (; i < ntot; i += stride) {
        float4 v; ushort4 o;
        if (i < n1) v = w1[i]; else v = w2[i - n1];
        o.x = f2bf(v.x); o.y = f2bf(v.y); o.z = f2bf(v.z); o.w = f2bf(v.w);
        if (i < n1) w1b[i] = o; else w2b[i - n1] = o;
    }
}

// ---------------------------------------------------------------------------
// One wave per token: logits = x[t] . rw[e], softmax over 8, top-2, gates.
__global__ __launch_bounds__(256) void router_kernel(
    const float* __restrict__ x, const float* __restrict__ rw,
    int* __restrict__ topki, float* __restrict__ topkg,
    float* __restrict__ blkps)
{
    int wave = threadIdx.x >> 6;
    int lane = threadIdx.x & 63;
    int t = blockIdx.x * 4 + wave;
    const float* xt = x + (size_t)t * DIMD;

    float acc[NE];
#pragma unroll
    for (int e = 0; e < NE; e++) acc[e] = 0.f;
    for (int i = 0; i < DIMD / 64; i++) {
        float xv = xt[lane + 64 * i];
#pragma unroll
        for (int e = 0; e < NE; e++) acc[e] += xv * rw[e * DIMD + lane + 64 * i];
    }
#pragma unroll
    for (int off = 32; off > 0; off >>= 1) {
#pragma unroll
        for (int e = 0; e < NE; e++) acc[e] += __shfl_down(acc[e], off);
    }

    __shared__ float ps[4][NE];
    if (lane == 0) {
        float m = acc[0];
#pragma unroll
        for (int e = 1; e < NE; e++) m = fmaxf(m, acc[e]);
        float ex[NE], s = 0.f;
#pragma unroll
        for (int e = 0; e < NE; e++) { ex[e] = expf(acc[e] - m); s += ex[e]; }
        float inv = 1.f / s;
#pragma unroll
        for (int e = 0; e < NE; e++) ps[wave][e] = ex[e] * inv;

        int i0 = 0; float l0 = acc[0];
#pragma unroll
        for (int e = 1; e < NE; e++) if (acc[e] > l0) { l0 = acc[e]; i0 = e; }
        int i1 = -1; float l1 = -3.4e38f;
#pragma unroll
        for (int e = 0; e < NE; e++) if (e != i0 && acc[e] > l1) { l1 = acc[e]; i1 = e; }
        float e1 = expf(l1 - l0);
        float g0 = 1.f / (1.f + e1);
        float g1 = e1 * g0;
        topki[t * 2 + 0] = i0; topki[t * 2 + 1] = i1;
        topkg[t * 2 + 0] = g0; topkg[t * 2 + 1] = g1;
    }
    __syncthreads();
    if (threadIdx.x < NE) {
        float s = ps[0][threadIdx.x] + ps[1][threadIdx.x] + ps[2][threadIdx.x] + ps[3][threadIdx.x];
        blkps[blockIdx.x * NE + threadIdx.x] = s;
    }
}

// ---------------------------------------------------------------------------
// Single block: counts, offsets, cursors, 256-row tile prefix, aux loss.
__global__ __launch_bounds__(256) void finalize_kernel(
    const int* __restrict__ topki, const float* __restrict__ blkps,
    int* __restrict__ counts, int* __restrict__ offsets, int* __restrict__ cursors,
    int* __restrict__ tileoff, float* __restrict__ aux_out)
{
    __shared__ float psum[NE];
    __shared__ int cnt[NE];
    int tid = threadIdx.x;
    if (tid < NE) { psum[tid] = 0.f; cnt[tid] = 0; }
    __syncthreads();

    float lp[NE]; int lc[NE];
#pragma unroll
    for (int e = 0; e < NE; e++) { lp[e] = 0.f; lc[e] = 0; }
    const float4* bp4 = (const float4*)blkps;
    for (int i = tid; i < 2048 * NE / 4; i += 256) {
        float4 v = bp4[i];
        int eb = (4 * i) & 7;   // 0 or 4
        lp[eb + 0] += v.x; lp[eb + 1] += v.y; lp[eb + 2] += v.z; lp[eb + 3] += v.w;
    }
    const int4* ti4 = (const int4*)topki;
    for (int i = tid; i < TOKS * 2 / 4; i += 256) {
        int4 v = ti4[i];
        lc[v.x]++; lc[v.y]++; lc[v.z]++; lc[v.w]++;
    }
#pragma unroll
    for (int e = 0; e < NE; e++) { atomicAdd(&psum[e], lp[e]); atomicAdd(&cnt[e], lc[e]); }
    __syncthreads();

    if (tid == 0) {
        int off = 0, to = 0;
        for (int e = 0; e < NE; e++) {
            counts[e] = cnt[e];
            offsets[e] = off; cursors[e] = off;
            tileoff[e] = to;
            off += cnt[e];
            to += (cnt[e] + 255) >> 8;     // 256-row tiles
        }
        offsets[NE] = off; tileoff[NE] = to;
        float aux = 0.f;
        for (int e = 0; e < NE; e++)
            aux += ((float)cnt[e] / (float)(TOKS * 2)) * (psum[e] / (float)TOKS);
        aux_out[0] = (float)NE * aux;
    }
}

// ---------------------------------------------------------------------------
// Build packed per-expert (token, gate) lists + inverse map token->position.
__global__ __launch_bounds__(64) void fill_kernel(
    const int* __restrict__ topki, const float* __restrict__ topkg,
    int* __restrict__ cursors, int* __restrict__ atok, float* __restrict__ agate,
    int* __restrict__ posinv)
{
    int lane = threadIdx.x;
    int t = blockIdx.x * 64 + lane;
    unsigned long long below = (lane == 63) ? 0x7FFFFFFFFFFFFFFFull
                                            : ((1ull << lane) - 1ull);
#pragma unroll
    for (int k = 0; k < 2; k++) {
        int e = topki[t * 2 + k];
        float g = topkg[t * 2 + k];
        for (int ee = 0; ee < NE; ee++) {
            bool pred = (e == ee);
            unsigned long long mask = __ballot(pred ? 1 : 0);
            if (mask) {
                int leader = __ffsll((unsigned long long)mask) - 1;
                int base = 0;
                if (lane == leader) base = atomicAdd(&cursors[ee], (int)__popcll(mask));
                base = __shfl(base, leader);
                if (pred) {
                    int pos = base + (int)__popcll(mask & below);
                    atok[pos] = t;
                    agate[pos] = g;
                    posinv[t * 2 + k] = pos;
                }
            }
        }
    }
}

// ---------------------------------------------------------------------------
// Gather x rows into packed assignment order, fp32 -> bf16.
__global__ __launch_bounds__(256) void gather_x_kernel(
    const float* __restrict__ x, const int* __restrict__ atok,
    ushort* __restrict__ Xg)
{
    int r = blockIdx.x;
    int tid = threadIdx.x;
    int tok = atok[r];
    float4 v = ((const float4*)(x + (size_t)tok * DIMD))[tid];
    ushort4 o;
    o.x = f2bf(v.x); o.y = f2bf(v.y); o.z = f2bf(v.z); o.w = f2bf(v.w);
    ((ushort4*)(Xg + (size_t)r * DIMD))[tid] = o;
}

// ===========================================================================
// 256x256 8-phase GEMM core. LDS chunk = 16 rows x 32 k (1 KB); A chunks
// 0..31 (row-subtile s, khalf kk -> s*2+kk), B chunks 32..63.
// Stage units (quadrant-aligned):
//   A0 = row-subtiles {0-3,8-11}   (MH=0 stripe: rows 0-63 & 128-191)
//   A1 = row-subtiles {4-7,12-15}  (MH=1 stripe)
//   B0 = col-subtiles s'%4 in {0,1} (NH=0 frags)
//   B1 = col-subtiles s'%4 in {2,3} (NH=1 frags)
// Per tile u: p1(MH0,NH0) reads A0,B0; p2(MH0,NH1) reads B1; p3(MH1,NH1)
// reads A1; p4(MH1,NH0) re-reads B0. Unit dead-after: A0:p1 B1:p2 A1:p3
// B0:p4 -> staged one phase later (one barrier of separation).
// ===========================================================================
template<int LD, int NT>
__device__ __forceinline__ void gemm8ph(
    const ushort* __restrict__ gApanel, const ushort* __restrict__ gBpanel,
    ushort (&lds)[2][64][512], floatx4 (&acc)[8][4],
    int lane, int wave, int wr, int wc, int l15, int quad)
{
    const bf16x8* C0 = (const bf16x8*)&lds[0][0][0];
    const bf16x8* C1 = (const bf16x8*)&lds[1][0][0];

    // Stage unit (0=A0,1=A1,2=B0,3=B1) of K-tile u into buffer bsel.
    // Each wave stages one 16-row subtile = 2 chunks (2 global_load_lds).
    auto stage_unit = [&](int bsel, int unit, int u) {
        int s, chunk;
        const ushort* panel;
        if (unit < 2) {
            s = (wave < 4 ? wave : wave + 4) + unit * 4;
            chunk = s * 2;
            panel = gApanel;
        } else {
            s = (wave & 1) + ((wave >> 1) * 4) + ((unit == 3) ? 2 : 0);
            chunk = 32 + s * 2;
            panel = gBpanel;
        }
        const ushort* s0 = panel + (size_t)(s * 16 + l15) * LD + u * 64 + quad * 8;
        __builtin_amdgcn_global_load_lds(GLOBAL_AS(s0),
            LDS_AS(&lds[bsel][chunk + 0][0]), 16, 0, 0);
        __builtin_amdgcn_global_load_lds(GLOBAL_AS(s0 + 32),
            LDS_AS(&lds[bsel][chunk + 1][0]), 16, 0, 0);
    };

#pragma unroll
    for (int i = 0; i < 8; i++)
#pragma unroll
        for (int j = 0; j < 4; j++) acc[i][j] = (floatx4){0.f, 0.f, 0.f, 0.f};

    bf16x8 af[4][2], bf[2][2];

    // Phase: read frags (RB first so the first MFMA's wait is short), stage
    // one unit, raw barrier (+sched_barrier guard, no memory clobber ->
    // NO hidden vmcnt(0) drain), MFMA cluster (compiler emits counted
    // lgkmcnt per use), optional BARE counted vmcnt, raw barrier.
#define PH(CB, MH, NH, RA, RB, DOSTAGE, SB, SUNIT, SU, DOWAIT, DEEP)          \
    {                                                                          \
        if (RB) {                                                              \
            _Pragma("unroll") for (int nj = 0; nj < 2; nj++) {                 \
                bf[nj][0] = CB[(32 + (wc * 4 + (NH)*2 + nj) * 2 + 0) * 64 + lane]; \
                bf[nj][1] = CB[(32 + (wc * 4 + (NH)*2 + nj) * 2 + 1) * 64 + lane]; \
            }                                                                  \
        }                                                                      \
        if (RA) {                                                              \
            _Pragma("unroll") for (int mi = 0; mi < 4; mi++) {                 \
                af[mi][0] = CB[((wr * 8 + (MH)*4 + mi) * 2 + 0) * 64 + lane];  \
                af[mi][1] = CB[((wr * 8 + (MH)*4 + mi) * 2 + 1) * 64 + lane];  \
            }                                                                  \
        }                                                                      \
        if (DOSTAGE) stage_unit(SB, SUNIT, SU);                                \
        __builtin_amdgcn_s_barrier();                                          \
        __builtin_amdgcn_sched_barrier(0);                                     \
        __builtin_amdgcn_s_setprio(1);                                         \
        _Pragma("unroll") for (int mi = 0; mi < 4; mi++)                       \
            _Pragma("unroll") for (int nj = 0; nj < 2; nj++)                   \
                _Pragma("unroll") for (int kk = 0; kk < 2; kk++)               \
                    acc[(MH)*4 + mi][(NH)*2 + nj] =                            \
                        __builtin_amdgcn_mfma_f32_16x16x32_bf16(               \
                            af[mi][kk], bf[nj][kk],                            \
                            acc[(MH)*4 + mi][(NH)*2 + nj], 0, 0, 0);           \
        __builtin_amdgcn_s_setprio(0);                                         \
        if (DOWAIT) {                                                          \
            if (DEEP) asm volatile("s_waitcnt vmcnt(0)");                      \
            else      asm volatile("s_waitcnt vmcnt(6)");                      \
            __builtin_amdgcn_sched_barrier(0);                                 \
        }                                                                      \
        __builtin_amdgcn_s_barrier();                                          \
        __builtin_amdgcn_sched_barrier(0);                                     \
    }

    // Prologue: tile0's 4 units + {A0,B1,A1}(1); wait vmcnt(6) -> tile0
    // complete, 6 in flight (steady invariant; B0(1) staged at tile0 p1).
    stage_unit(0, 0, 0);   // A0(0)
    stage_unit(0, 2, 0);   // B0(0)
    stage_unit(0, 3, 0);   // B1(0)
    stage_unit(0, 1, 0);   // A1(0)
    stage_unit(1, 0, 1);   // A0(1)
    stage_unit(1, 3, 1);   // B1(1)
    stage_unit(1, 1, 1);   // A1(1)
    asm volatile("s_waitcnt vmcnt(6)");
    __builtin_amdgcn_sched_barrier(0);
    __builtin_amdgcn_s_barrier();
    __builtin_amdgcn_sched_barrier(0);

    for (int u = 0; u < NT; u += 2) {
        // ---- K-tile u (buf0) ----
        PH(C0, 0, 0, 1, 1, (u + 1 < NT), 1, 2, u + 1, 0, 0);              // p1 +B0(u+1)
        PH(C0, 0, 1, 0, 1, (u + 2 < NT), 0, 0, u + 2, 0, 0);              // p2 +A0(u+2)
        PH(C0, 1, 1, 1, 0, (u + 2 < NT), 0, 3, u + 2, 0, 0);              // p3 +B1(u+2)
        PH(C0, 1, 0, 0, 1, (u + 2 < NT), 0, 1, u + 2, 1, (u + 2 >= NT));  // p4 +A1(u+2), wait
        // ---- K-tile u+1 (buf1) ----
        PH(C1, 0, 0, 1, 1, (u + 2 < NT), 0, 2, u + 2, 0, 0);              // p1 +B0(u+2)
        PH(C1, 0, 1, 0, 1, (u + 3 < NT), 1, 0, u + 3, 0, 0);              // p2 +A0(u+3)
        PH(C1, 1, 1, 1, 0, (u + 3 < NT), 1, 3, u + 3, 0, 0);              // p3 +B1(u+3)
        PH(C1, 1, 0, 0, 1, (u + 3 < NT), 1, 1, u + 3, 1, (u + 3 >= NT));  // p4 +A1(u+3), wait
    }
#undef PH
}

// ---------------------------------------------------------------------------
// Phase 1: H = gelu(Xg @ w1b[e]^T + b1[e]),  M=sum cnt, N=2048, K=1024.
__global__ __launch_bounds__(512, 2) void phase1_kernel(
    const ushort* __restrict__ Xg, const ushort* __restrict__ w1b,
    const float* __restrict__ b1,
    const int* __restrict__ counts, const int* __restrict__ offsets,
    const int* __restrict__ tileoff, unsigned short* __restrict__ Hbuf)
{
    const int NCOLT = HID / 256;   // 8 col tiles
    int total = tileoff[NE] * NCOLT;
    int idx = xcd_remap((int)blockIdx.x, (int)gridDim.x);
    if (idx >= total) return;
    int ct = idx & (NCOLT - 1);
    int rowt = idx / NCOLT;
    int e = 0;
    while (rowt >= tileoff[e + 1]) e++;
    int row0 = (rowt - tileoff[e]) * 256;
    int cnt = counts[e];
    int base = offsets[e];
    int colbase = ct * 256;

    __shared__ ushort lds[2][64][512];   // 128 KiB

    int tid = threadIdx.x;
    int lane = tid & 63;
    int wave = tid >> 6;
    int wr = wave >> 2, wc = wave & 3;
    int l15 = lane & 15, quad = lane >> 4;

    const ushort* gApanel = Xg + (size_t)(base + row0) * DIMD;
    const ushort* gBpanel = w1b + (size_t)e * HID * DIMD + (size_t)colbase * DIMD;

    floatx4 acc[8][4];
    gemm8ph<DIMD, DIMD / 64>(gApanel, gBpanel, lds, acc, lane, wave, wr, wc, l15, quad);

    // epilogue: bias + exact GELU, bf16 store. C/D: col=lane&15, row=quad*4+reg
    float b1v[4];
#pragma unroll
    for (int j = 0; j < 4; j++)
        b1v[j] = b1[e * HID + colbase + 64 * wc + 16 * j + l15];
#pragma unroll
    for (int i = 0; i < 8; i++) {
#pragma unroll
        for (int rr = 0; rr < 4; rr++) {
            int pr = row0 + 128 * wr + 16 * i + quad * 4 + rr;
            if (pr < cnt) {
                size_t hrow = (size_t)(base + pr) * HID;
#pragma unroll
                for (int j = 0; j < 4; j++) {
                    int col = colbase + 64 * wc + 16 * j + l15;
                    float v = acc[i][j][rr] + b1v[j];
                    v = 0.5f * v * (1.f + erff(v * 0.70710678118654752f));
                    Hbuf[hrow + col] = f2bf(v);
                }
            }
        }
    }
}

// ---------------------------------------------------------------------------
// Phase 2: Y = H @ w2b[e]^T,  M=sum cnt, N=1024, K=2048.
__global__ __launch_bounds__(512, 2) void phase2_kernel(
    const ushort* __restrict__ Hbuf, const ushort* __restrict__ w2b,
    const int* __restrict__ counts, const int* __restrict__ offsets,
    const int* __restrict__ tileoff, ushort* __restrict__ Y)
{
    const int NCOLT = DIMD / 256;  // 4 col tiles
    int total = tileoff[NE] * NCOLT;
    int idx = xcd_remap((int)blockIdx.x, (int)gridDim.x);
    if (idx >= total) return;
    int ct = idx & (NCOLT - 1);
    int rowt = idx / NCOLT;
    int e = 0;
    while (rowt >= tileoff[e + 1]) e++;
    int row0 = (rowt - tileoff[e]) * 256;
    int cnt = counts[e];
    int base = offsets[e];
    int colbase = ct * 256;

    __shared__ ushort lds[2][64][512];   // 128 KiB

    int tid = threadIdx.x;
    int lane = tid & 63;
    int wave = tid >> 6;
    int wr = wave >> 2, wc = wave & 3;
    int l15 = lane & 15, quad = lane >> 4;

    const ushort* gApanel = Hbuf + (size_t)(base + row0) * HID;
    const ushort* gBpanel = w2b + (size_t)e * DIMD * HID + (size_t)colbase * HID;

    floatx4 acc[8][4];
    gemm8ph<HID, HID / 64>(gApanel, gBpanel, lds, acc, lane, wave, wr, wc, l15, quad);

    // epilogue: plain bf16 store (bias+gate applied in combine)
#pragma unroll
    for (int i = 0; i < 8; i++) {
#pragma unroll
        for (int rr = 0; rr < 4; rr++) {
            int pr = row0 + 128 * wr + 16 * i + quad * 4 + rr;
            if (pr < cnt) {
                size_t yrow = (size_t)(base + pr) * DIMD;
#pragma unroll
                for (int j = 0; j < 4; j++) {
                    int col = colbase + 64 * wc + 16 * j + l15;
                    Y[yrow + col] = f2bf(acc[i][j][rr]);
                }
            }
        }
    }
}

// ---------------------------------------------------------------------------
// Combine: out[t,:] = g0*(Y[p0,:]+b2[e0,:]) + g1*(Y[p1,:]+b2[e1,:]).
__global__ __launch_bounds__(256) void combine_kernel(
    const ushort* __restrict__ Y, const float* __restrict__ b2,
    const int* __restrict__ topki, const float* __restrict__ topkg,
    const int* __restrict__ posinv, float* __restrict__ out)
{
    int wave = threadIdx.x >> 6;
    int lane = threadIdx.x & 63;
    int t = blockIdx.x * 4 + wave;
    int e0 = topki[t * 2 + 0], e1 = topki[t * 2 + 1];
    float g0 = topkg[t * 2 + 0], g1 = topkg[t * 2 + 1];
    int p0 = posinv[t * 2 + 0], p1 = posinv[t * 2 + 1];

    const ushort4* y0 = (const ushort4*)(Y + (size_t)p0 * DIMD);
    const ushort4* y1 = (const ushort4*)(Y + (size_t)p1 * DIMD);
    const float4* b20 = (const float4*)(b2 + (size_t)e0 * DIMD);
    const float4* b21 = (const float4*)(b2 + (size_t)e1 * DIMD);
    float4* o4 = (float4*)(out + (size_t)t * DIMD);

#pragma unroll
    for (int c = 0; c < DIMD / 4 / 64; c++) {   // 4 iterations
        int i = lane + 64 * c;
        ushort4 a = y0[i], b = y1[i];
        float4 ba = b20[i], bb = b21[i];
        float4 r;
        r.x = g0 * (bf2f(a.x) + ba.x) + g1 * (bf2f(b.x) + bb.x);
        r.y = g0 * (bf2f(a.y) + ba.y) + g1 * (bf2f(b.y) + bb.y);
        r.z = g0 * (bf2f(a.z) + ba.z) + g1 * (bf2f(b.z) + bb.z);
        r.w = g0 * (bf2f(a.w) + ba.w) + g1 * (bf2f(b.w) + bb.w);
        o4[i] = r;
    }
}

// ---------------------------------------------------------------------------
extern "C" void kernel_launch(void* const* d_in, const int* in_sizes, int n_in,
                              void* d_out, int out_size, void* d_ws, size_t ws_size,
                              hipStream_t stream) {
    const float* x  = (const float*)d_in[0];
    const float* rw = (const float*)d_in[1];
    const float* w1 = (const float*)d_in[2];
    const float* b1 = (const float*)d_in[3];
    const float* w2 = (const float*)d_in[4];
    const float* b2 = (const float*)d_in[5];
    float* out = (float*)d_out;

    char* ws = (char*)d_ws;
    int*   counts  = (int*)(ws + OFF_COUNTS);
    int*   offsets = (int*)(ws + OFF_OFFSETS);
    int*   cursors = (int*)(ws + OFF_CURSORS);
    int*   tileoff = (int*)(ws + OFF_TILEOFF);
    int*   topki   = (int*)(ws + OFF_TOPKI);
    float* topkg   = (float*)(ws + OFF_TOPKG);
    float* blkps   = (float*)(ws + OFF_BLKPS);
    int*   atok    = (int*)(ws + OFF_ATOK);
    float* agate   = (float*)(ws + OFF_AGATE);
    int*   posinv  = (int*)(ws + OFF_PINV);
    ushort* Xg     = (ushort*)(ws + OFF_XG);
    ushort* w1b    = (ushort*)(ws + OFF_W1B);
    ushort* w2b    = (ushort*)(ws + OFF_W2B);
    ushort* Hbuf   = (ushort*)(ws + OFF_H);
    ushort* Y      = (ushort*)(ws + OFF_Y);

    // weight conversions (independent of routing), one pass
    convert_w_kernel<<<8192, 256, 0, stream>>>(
        (const float4*)w1, (ushort4*)w1b, NE * HID * DIMD / 4,
        (const float4*)w2, (ushort4*)w2b, NE * DIMD * HID / 4);

    router_kernel<<<TOKS / 4, 256, 0, stream>>>(x, rw, topki, topkg, blkps);
    finalize_kernel<<<1, 256, 0, stream>>>(topki, blkps, counts, offsets, cursors,
                                           tileoff, out + (size_t)TOKS * DIMD);
    fill_kernel<<<TOKS / 64, 64, 0, stream>>>(topki, topkg, cursors, atok, agate,
                                              posinv);
    gather_x_kernel<<<TOKS * 2, 256, 0, stream>>>(x, atok, Xg);

    // worst-case 256-row tiles: sum_e ceil(cnt_e/256) <= 16384/256 + 7 = 71
    phase1_kernel<<<71 * (HID / 256), 512, 0, stream>>>(
        Xg, w1b, b1, counts, offsets, tileoff, Hbuf);
    phase2_kernel<<<71 * (DIMD / 256), 512, 0, stream>>>(
        Hbuf, w2b, counts, offsets, tileoff, Y);
    combine_kernel<<<TOKS / 4, 256, 0, stream>>>(Y, b2, topki, topkg, posinv, out);
}